// Round 13
// baseline (394.365 us; speedup 1.0000x reference)
//
#include <hip/hip_runtime.h>
#include <stdint.h>

#define B_ 4
#define T_ 2048
#define D_ 1024
#define N_ 1024
#define TC 16
#define NCH (T_/TC)
#define SQN 6   // squaring GEMMs after gram; +1 effective doubling via fused Frobenius

typedef __attribute__((ext_vector_type(4))) float f32x4;
typedef __attribute__((ext_vector_type(8))) short bf16x8;
typedef __attribute__((ext_vector_type(4))) unsigned short us4;

__device__ __forceinline__ unsigned short f2bf(float f){
  unsigned int u = __float_as_uint(f);
  return (unsigned short)((u + 0x7fffu + ((u >> 16) & 1u)) >> 16);
}
__device__ __forceinline__ float bf2f(unsigned short h){
  return __uint_as_float(((unsigned int)h) << 16);
}

// inverse spectral scale from trace chain (z=0: W_in, z=1: W_out)
__device__ __forceinline__ float inv_scale(const float* __restrict__ sc, int z){
  float ll = 0.f, w = 1.f, t = 1.f;
  #pragma unroll
  for (int i = 0; i <= SQN; i++){
    t = sc[8 + 2*i + z];
    ll += w * __logf(t);
    w *= 0.5f;
  }
  float F = sc[8 + 2*(SQN+1) + z];
  ll += w * __logf(F / (t*t));
  float sig = fmaxf(__expf(0.5f * ll), 1e-5f);
  return 1.f / fmaxf(sig, 1.f);
}

__device__ __forceinline__ float softplusf(float x){
  return (x > 0.f) ? (x + __logf(1.f + __expf(-x))) : __logf(1.f + __expf(x));
}
__device__ __forceinline__ float tanhfastf(float x){
  float e = __expf(2.f * x);
  return 1.f - 2.f/(e + 1.f);
}
__device__ __forceinline__ void abc_from(float pin, float draw, float braw, float craw,
    float alpha, float ginv, float& a_o, float& bu_o, float& c_o){
  float sp = softplusf(draw);
  float av = __expf(-sp * alpha);
  av = fminf(av, 1.f - 1e-4f);
  float bv = tanhfastf(braw);
  float cv = tanhfastf(craw);
  float p = av*av + cv*cv;
  float r = bv*bv;
  float q = av*bv;
  float pr = p - r;
  float disc = pr*pr + 4.f*q*q;
  float lam = 0.5f*(p + r + sqrtf(disc + 1e-12f));
  float inv = fminf(rsqrtf(lam + 1e-12f), 1.f);
  a_o = av * inv;
  c_o = cv * inv;
  bu_o = (bv * inv) * (pin * ginv);
}

// ---- fused fp32->bf16 conversion + INTERLEAVE of weight rows + sc zero-init ----
// Wcat16 row (4n+s): s=0 -> W_in[n], s=1..3 -> pn_w[(s-1)*N + n] (delta, b, c).
// => P = u @ Wcat^T has layout [t][n][4]: all 4 gate streams adjacent per n.
#define U4    2097152
#define WIN4   262144
#define PNW4   786432
#define WOUT4  262144
#define CONV_BLOCKS ((U4 + WIN4 + PNW4 + WOUT4 + 255)/256)

__global__ void k_convert_all(const float* __restrict__ u, const float* __restrict__ Win,
                              const float* __restrict__ pnw, const float* __restrict__ Wout,
                              unsigned short* __restrict__ u16, unsigned short* __restrict__ Wcat16,
                              unsigned short* __restrict__ Wout16, float* __restrict__ sc){
  if (blockIdx.x == 0 && threadIdx.x < 64) sc[threadIdx.x] = 0.f;
  long i = (long)blockIdx.x * 256 + threadIdx.x;
  const float* src; long o; size_t didx; unsigned short* dbuf;
  if (i < U4){
    src = u; o = i; dbuf = u16; didx = (size_t)o;
  } else if (i < U4+WIN4){
    o = i - U4; src = Win;
    int n = (int)(o >> 8), c4 = (int)(o & 255);
    dbuf = Wcat16; didx = (size_t)(4*n)*256 + c4;
  } else if (i < U4+WIN4+PNW4){
    o = i - (U4+WIN4); src = pnw;
    int m = (int)(o >> 8), c4 = (int)(o & 255);
    int s = (m >> 10) + 1, n = m & 1023;
    dbuf = Wcat16; didx = (size_t)(4*n + s)*256 + c4;
  } else if (i < U4+WIN4+PNW4+WOUT4){
    o = i - (U4+WIN4+PNW4); src = Wout; dbuf = Wout16; didx = (size_t)o;
  } else return;
  float4 v = ((const float4*)src)[o];
  us4 w;
  w.x = f2bf(v.x); w.y = f2bf(v.y); w.z = f2bf(v.z); w.w = f2bf(v.w);
  ((us4*)dbuf)[didx] = w;
}

__device__ __forceinline__ void load_lds16(const unsigned short* g, unsigned short* l){
  __builtin_amdgcn_global_load_lds((const __attribute__((address_space(1))) void*)g,
                                   (__attribute__((address_space(3))) void*)l, 16, 0, 0);
}

// ---- big GEMM: C[M,N] = (A[M,K] * B[N,K]^T) * (step>=0 ? inv_scale(step) : 1) ----
// 128x128 tile, proven m97-structure (89.5us P / ~23us out). Pure GEMM, no fusion.
template<int OUTBF16>
__global__ __launch_bounds__(256) void k_gemm(
    const unsigned short* __restrict__ A,
    const unsigned short* __restrict__ Bmat,
    void* __restrict__ C0,
    int M, int N, int K,
    const float* __restrict__ sc, int step)
{
  __shared__ alignas(16) unsigned short As[128*64];
  __shared__ alignas(16) unsigned short Bs[128*64];
  const int tid = threadIdx.x;
  const int wid = tid >> 6;
  const int lane = tid & 63;
  const int bn = blockIdx.x, bm = blockIdx.y;

  char* C = (char*)C0;
  float outscale = (step >= 0) ? inv_scale(sc, step) : 1.f;

  const int wr = wid >> 1, wc = wid & 1;
  const int rg = lane >> 3;
  const int cby = (lane & 7) << 4;
  const int srow0 = wid * 32;
  const int frow = lane & 15;
  const int kgrp = lane >> 4;

  const unsigned short* ap[4];
  const unsigned short* bp[4];
  unsigned short* adst[4];
  unsigned short* bdst[4];
  #pragma unroll
  for (int i = 0; i < 4; i++){
    int r = srow0 + i*8 + rg;
    int cb = cby ^ ((r & 7) << 4);
    ap[i] = A    + (size_t)(bm*128 + r)*K + (cb >> 1);
    bp[i] = Bmat + (size_t)(bn*128 + r)*K + (cb >> 1);
    adst[i] = As + (srow0 + i*8)*64;
    bdst[i] = Bs + (srow0 + i*8)*64;
  }
  int aoff[4][2], boff[4][2];
  #pragma unroll
  for (int m = 0; m < 4; m++){
    int r = wr*64 + m*16 + frow;
    #pragma unroll
    for (int kk = 0; kk < 2; kk++)
      aoff[m][kk] = r*128 + ((kk*64 + kgrp*16) ^ ((r & 7) << 4));
  }
  #pragma unroll
  for (int n2 = 0; n2 < 4; n2++){
    int r = wc*64 + n2*16 + frow;
    #pragma unroll
    for (int kk = 0; kk < 2; kk++)
      boff[n2][kk] = r*128 + ((kk*64 + kgrp*16) ^ ((r & 7) << 4));
  }

  f32x4 acc[4][4] = {};

  for (int kt = 0; kt < K; kt += 64){
    #pragma unroll
    for (int i = 0; i < 4; i++){
      load_lds16(ap[i], adst[i]);
      load_lds16(bp[i], bdst[i]);
      ap[i] += 64; bp[i] += 64;
    }
    __syncthreads();
    #pragma unroll
    for (int kk = 0; kk < 2; kk++){
      bf16x8 af[4], bfv[4];
      #pragma unroll
      for (int m = 0; m < 4; m++)
        af[m] = *(const bf16x8*)((const char*)As + aoff[m][kk]);
      #pragma unroll
      for (int n2 = 0; n2 < 4; n2++)
        bfv[n2] = *(const bf16x8*)((const char*)Bs + boff[n2][kk]);
      #pragma unroll
      for (int m = 0; m < 4; m++)
        #pragma unroll
        for (int n2 = 0; n2 < 4; n2++)
          acc[m][n2] = __builtin_amdgcn_mfma_f32_16x16x32_bf16(af[m], bfv[n2], acc[m][n2], 0, 0, 0);
    }
    __syncthreads();
  }

  const int row0 = bm*128 + wr*64;
  const int col0 = bn*128 + wc*64 + frow;
  #pragma unroll
  for (int m = 0; m < 4; m++){
    #pragma unroll
    for (int n2 = 0; n2 < 4; n2++){
      const int col = col0 + n2*16;
      const int rb = row0 + m*16 + kgrp*4;
      #pragma unroll
      for (int j = 0; j < 4; j++){
        float v = acc[m][n2][j] * outscale;
        if (OUTBF16) ((unsigned short*)C)[(size_t)(rb + j)*N + col] = f2bf(v);
        else         ((float*)C)[(size_t)(rb + j)*N + col] = v;
      }
    }
  }
}

// ---- triangular squaring-chain GEMM (C = X*X^T symmetric, upper tiles only) ----
__global__ __launch_bounds__(256) void k_sq(
    const unsigned short* __restrict__ A0, unsigned short* __restrict__ C0,
    const unsigned short* __restrict__ A1, unsigned short* __restrict__ C1,
    float* __restrict__ sc, int step)
{
  __shared__ alignas(16) unsigned short As0[64*128], Bs0[64*128];
  __shared__ alignas(16) unsigned short As1[64*128], Bs1[64*128];
  const int tid = threadIdx.x;
  const int wid = tid >> 6;
  const int lane = tid & 63;
  const int z = blockIdx.z;

  int x = blockIdx.x, bm = 0;
  while (x >= 16 - bm){ x -= 16 - bm; bm++; }
  const int bn = bm + x;

  const unsigned short* A = z ? A1 : A0;
  unsigned short* C = z ? C1 : C0;
  const size_t rs = (step == 0 && z == 0) ? 4096 : 1024;
  float outscale = 1.f;
  if (step > 0){ float t = sc[8 + (step-1)*2 + z]; outscale = 1.f/(t*t); }

  const int wr = wid >> 1, wc = wid & 1;
  const int frow = lane & 15;
  const int kgrp = lane >> 4;

  const int srl = lane >> 4;
  const int sgr = lane & 15;
  const int swzr = wid*4 + srl;
  const int scol_e = ((sgr ^ swzr) << 3);

  const size_t Arow = (size_t)bm * 64;
  const size_t Brow = (size_t)bn * 64;

  f32x4 acc[2][2] = {};

  auto stage = [&](unsigned short* as, unsigned short* bs, int t){
    const int kt = t * 128;
    #pragma unroll
    for (int i = 0; i < 4; i++){
      int r = i*16 + wid*4 + srl;
      load_lds16(A + (Arow + r)*rs + kt + scol_e, as + (i*16 + wid*4)*128);
      load_lds16(A + (Brow + r)*rs + kt + scol_e, bs + (i*16 + wid*4)*128);
    }
  };

  auto compute = [&](const unsigned short* as, const unsigned short* bs){
    #pragma unroll
    for (int ks = 0; ks < 4; ks++){
      const int kb = ks*64 + kgrp*16;
      bf16x8 af[2], bfv[2];
      #pragma unroll
      for (int m = 0; m < 2; m++){
        int r = wr*32 + m*16 + frow;
        af[m] = *(const bf16x8*)((const char*)as + r*256 + (kb ^ (frow << 4)));
      }
      #pragma unroll
      for (int n2 = 0; n2 < 2; n2++){
        int r = wc*32 + n2*16 + frow;
        bfv[n2] = *(const bf16x8*)((const char*)bs + r*256 + (kb ^ (frow << 4)));
      }
      #pragma unroll
      for (int m = 0; m < 2; m++)
        #pragma unroll
        for (int n2 = 0; n2 < 2; n2++)
          acc[m][n2] = __builtin_amdgcn_mfma_f32_16x16x32_bf16(af[m], bfv[n2], acc[m][n2], 0, 0, 0);
    }
  };

  stage(As0, Bs0, 0);
  __syncthreads();
  for (int t2 = 0; t2 < 8; t2 += 2){
    if (t2 + 1 < 8) stage(As1, Bs1, t2 + 1);
    compute(As0, Bs0);
    __syncthreads();
    if (t2 + 2 < 8) stage(As0, Bs0, t2 + 2);
    compute(As1, Bs1);
    __syncthreads();
  }

  const int row0 = bm*64 + wr*32;
  const int col0 = bn*64 + wc*32 + frow;
  float fr = 0.f;
  #pragma unroll
  for (int m = 0; m < 2; m++){
    #pragma unroll
    for (int n2 = 0; n2 < 2; n2++){
      const int col = col0 + n2*16;
      const int rb = row0 + m*16 + kgrp*4;
      us4 tw;
      #pragma unroll
      for (int j = 0; j < 4; j++){
        float v = acc[m][n2][j] * outscale;
        unsigned short h = f2bf(v);
        C[(size_t)(rb + j)*1024 + col] = h;
        tw[j] = h;
        fr += v*v;
      }
      if (bm != bn)
        *(us4*)(C + (size_t)col*1024 + rb) = tw;
    }
  }
  if (bm == bn && wr == wc){
    int j = frow - kgrp*4;
    if (j >= 0 && j < 4){
      float d = (acc[0][0][j] + acc[1][1][j]) * outscale;
      atomicAdd(&sc[8 + step*2 + z], d);
    }
  }
  if (step == SQN){
    if (bm != bn) fr *= 2.f;
    #pragma unroll
    for (int off = 32; off; off >>= 1) fr += __shfl_down(fr, off, 64);
    if (lane == 0) atomicAdd(&sc[8 + 2*(SQN+1) + z], fr);
  }
}

// ---- k_gate: per-chunk (A,S). LDS-staged P chunk (64KB DMA via global_load_lds)
// for full-BW reads; compute from LDS. grid (NCH, 2, B_) = 1024 blocks.
__global__ __launch_bounds__(256) void k_gate(
    const unsigned short* __restrict__ P,
    const float* __restrict__ alog, const float* __restrict__ dbias,
    const float* __restrict__ pnb, const float* __restrict__ lgam,
    const float* __restrict__ sc,
    float* __restrict__ Asum, float* __restrict__ Ssum)
{
  __shared__ alignas(16) unsigned short Ps[16*2048];   // 16 rows x 4KB = 64KB
  const int tid = threadIdx.x;
  const int wid = tid >> 6;
  const int n0 = blockIdx.y*512 + tid*2;
  const int ch = blockIdx.x, b = blockIdx.z;

  // async DMA: whole chunk in flight (16 x 16B per thread, no VGPR cost)
  const unsigned short* Pbase = P + (size_t)(b*T_ + ch*TC)*4096 + blockIdx.y*2048;
  #pragma unroll
  for (int i = 0; i < TC; i++)
    load_lds16(Pbase + (size_t)i*4096 + tid*8, Ps + i*2048 + wid*512);

  const float ginv = __expf(lgam[0]) * inv_scale(sc, 0);
  float alpha[2], bd[2], bb[2], bc[2], A[2] = {1.f,1.f}, S[2] = {0.f,0.f};
  #pragma unroll
  for (int j = 0; j < 2; j++){
    alpha[j] = softplusf(alog[n0+j]);
    bd[j] = dbias[n0+j] + pnb[n0+j];
    bb[j] = pnb[N_ + n0+j];
    bc[j] = pnb[2*N_ + n0+j];
  }
  __syncthreads();                                     // drains DMA (vmcnt 0)

  #pragma unroll
  for (int i = 0; i < TC; i++){
    bf16x8 e = *(const bf16x8*)(Ps + i*2048 + tid*8);
    #pragma unroll
    for (int j = 0; j < 2; j++){
      const int o = j*4;
      float a, bu, c;
      abc_from(bf2f((unsigned short)e[o]),   bf2f((unsigned short)e[o+1]) + bd[j],
               bf2f((unsigned short)e[o+2]) + bb[j], bf2f((unsigned short)e[o+3]) + bc[j],
               alpha[j], ginv, a, bu, c);
      S[j] = fmaf(a, S[j], bu);
      A[j] *= a;
    }
  }
  const size_t idx = (size_t)(b*NCH + ch)*N_ + n0;
  *(float2*)(Asum + idx) = make_float2(A[0], A[1]);
  *(float2*)(Ssum + idx) = make_float2(S[0], S[1]);
}

// ---- k_scan3: prefix over Asum/Ssum (pass2 fused) + gate recompute + y_hat ----
// Same LDS-staged P chunk. grid (NCH, 2, B_).
__global__ __launch_bounds__(256) void k_scan3(
    const unsigned short* __restrict__ P,
    const float* __restrict__ alog, const float* __restrict__ dbias,
    const float* __restrict__ pnb, const float* __restrict__ lgam,
    const float* __restrict__ sc,
    const float* __restrict__ Asum, const float* __restrict__ Ssum,
    const float* __restrict__ z0, unsigned short* __restrict__ yh)
{
  __shared__ alignas(16) unsigned short Ps[16*2048];
  const int tid = threadIdx.x;
  const int wid = tid >> 6;
  const int n0 = blockIdx.y*512 + tid*2;
  const int ch = blockIdx.x, b = blockIdx.z;

  const unsigned short* Pbase = P + (size_t)(b*T_ + ch*TC)*4096 + blockIdx.y*2048;
  #pragma unroll
  for (int i = 0; i < TC; i++)
    load_lds16(Pbase + (size_t)i*4096 + tid*8, Ps + i*2048 + wid*512);

  const float ginv = __expf(lgam[0]) * inv_scale(sc, 0);
  float alpha[2], bd[2], bb[2], bc[2], z[2];
  #pragma unroll
  for (int j = 0; j < 2; j++){
    alpha[j] = softplusf(alog[n0+j]);
    bd[j] = dbias[n0+j] + pnb[n0+j];
    bb[j] = pnb[N_ + n0+j];
    bc[j] = pnb[2*N_ + n0+j];
    z[j] = z0[b*N_ + n0 + j];
  }
  for (int c2 = 0; c2 < ch; c2++){
    const size_t idx = (size_t)(b*NCH + c2)*N_ + n0;
    float2 Av = *(const float2*)(Asum + idx);
    float2 Sv = *(const float2*)(Ssum + idx);
    z[0] = fmaf(Av.x, z[0], Sv.x);
    z[1] = fmaf(Av.y, z[1], Sv.y);
  }
  __syncthreads();                                     // drains DMA

  unsigned short* Y = yh + (size_t)(b*T_ + ch*TC)*N_ + n0;
  #pragma unroll
  for (int i = 0; i < TC; i++){
    bf16x8 e = *(const bf16x8*)(Ps + i*2048 + tid*8);
    unsigned int ow = 0;
    #pragma unroll
    for (int j = 0; j < 2; j++){
      const int o = j*4;
      float a, bu, c;
      abc_from(bf2f((unsigned short)e[o]),   bf2f((unsigned short)e[o+1]) + bd[j],
               bf2f((unsigned short)e[o+2]) + bb[j], bf2f((unsigned short)e[o+3]) + bc[j],
               alpha[j], ginv, a, bu, c);
      float yv = c * z[j];
      z[j] = fmaf(a, z[j], bu);
      ow |= ((unsigned int)f2bf(yv)) << (16*j);
    }
    *(unsigned int*)Y = ow;
    Y += N_;
  }
}

extern "C" void kernel_launch(void* const* d_in, const int* in_sizes, int n_in,
                              void* d_out, int out_size, void* d_ws, size_t ws_size,
                              hipStream_t stream)
{
  const float* u    = (const float*)d_in[0];
  const float* z0   = (const float*)d_in[1];
  const float* Win  = (const float*)d_in[2];
  const float* Wout = (const float*)d_in[3];
  const float* pnw  = (const float*)d_in[4];
  const float* pnb  = (const float*)d_in[5];
  const float* alog = (const float*)d_in[6];
  const float* dbias= (const float*)d_in[7];
  const float* lgam = (const float*)d_in[8];

  char* ws = (char*)d_ws;
  size_t off = 0;
  auto alloc = [&](size_t bytes) -> void* {
    void* p = ws + off;
    off += (bytes + 255) & ~(size_t)255;
    return p;
  };
  float*          sc     = (float*)         alloc(1024);
  unsigned short* u16    = (unsigned short*)alloc((size_t)8192*1024*2);
  unsigned short* Wcat16 = (unsigned short*)alloc((size_t)4096*1024*2);
  unsigned short* Wout16 = (unsigned short*)alloc((size_t)1024*1024*2);
  unsigned short* P16    = (unsigned short*)alloc((size_t)8192*4096*2);
  unsigned short* yh16   = (unsigned short*)alloc((size_t)8192*1024*2);
  unsigned short* Hping  = (unsigned short*)alloc((size_t)2*1024*1024*2);
  unsigned short* Hpong  = (unsigned short*)alloc((size_t)2*1024*1024*2);
  float*          Asum   = (float*)alloc((size_t)B_*NCH*N_*4);
  float*          Ssum   = (float*)alloc((size_t)B_*NCH*N_*4);

  k_convert_all<<<CONV_BLOCKS, 256, 0, stream>>>(u, Win, pnw, Wout, u16, Wcat16, Wout16, sc);

  // spectral-norm chains: gram (step 0) + SQN squarings (triangular); frob fused in last step
  dim3 gsq(136, 1, 2);
  k_sq<<<gsq, 256, 0, stream>>>(Wcat16, Hping, Wout16, Hping + (size_t)1024*1024, sc, 0);
  unsigned short* hin = Hping;
  unsigned short* hout = Hpong;
  for (int s = 1; s <= SQN; s++){
    k_sq<<<gsq, 256, 0, stream>>>(hin, hout, hin + (size_t)1024*1024, hout + (size_t)1024*1024, sc, s);
    unsigned short* t = hin; hin = hout; hout = t;
  }

  // P = u @ Wcat^T  (bf16 out, interleaved [t][n][4]; inv_scale applied in gate/scan)
  dim3 g1(4096/128, 8192/128);
  k_gemm<1><<<g1, 256, 0, stream>>>(u16, Wcat16, P16, 8192, 4096, 1024, sc, -1);

  // per-chunk (A,S)
  dim3 gg(NCH, 2, B_);
  k_gate<<<gg, 256, 0, stream>>>(P16, alog, dbias, pnb, lgam, sc, Asum, Ssum);

  // fused pass2+pass3: prefix + gate recompute + y_hat
  k_scan3<<<gg, 256, 0, stream>>>(P16, alog, dbias, pnb, lgam, sc, Asum, Ssum, z0, yh16);

  // y = (y_hat @ W_out^T) * inv_scale(sc,1)  (fp32 out)
  dim3 g2(1024/128, 8192/128);
  k_gemm<0><<<g2, 256, 0, stream>>>(yh16, Wout16, d_out, 8192, 1024, 1024, sc, 1);
}

// Round 14
// 343.930 us; speedup vs baseline: 1.1466x; 1.1466x over previous
//
#include <hip/hip_runtime.h>
#include <stdint.h>

#define B_ 4
#define T_ 2048
#define D_ 1024
#define N_ 1024
#define TC 16
#define NCH (T_/TC)
#define SQN 6   // squaring GEMMs after gram; +1 effective doubling via fused Frobenius

typedef __attribute__((ext_vector_type(4))) float f32x4;
typedef __attribute__((ext_vector_type(8))) short bf16x8;
typedef __attribute__((ext_vector_type(4))) unsigned short us4;

__device__ __forceinline__ unsigned short f2bf(float f){
  unsigned int u = __float_as_uint(f);
  return (unsigned short)((u + 0x7fffu + ((u >> 16) & 1u)) >> 16);
}
__device__ __forceinline__ float bf2f(unsigned short h){
  return __uint_as_float(((unsigned int)h) << 16);
}

// inverse spectral scale from trace chain (z=0: W_in, z=1: W_out)
__device__ __forceinline__ float inv_scale(const float* __restrict__ sc, int z){
  float ll = 0.f, w = 1.f, t = 1.f;
  #pragma unroll
  for (int i = 0; i <= SQN; i++){
    t = sc[8 + 2*i + z];
    ll += w * __logf(t);
    w *= 0.5f;
  }
  float F = sc[8 + 2*(SQN+1) + z];
  ll += w * __logf(F / (t*t));
  float sig = fmaxf(__expf(0.5f * ll), 1e-5f);
  return 1.f / fmaxf(sig, 1.f);
}

__device__ __forceinline__ float softplusf(float x){
  return (x > 0.f) ? (x + __logf(1.f + __expf(-x))) : __logf(1.f + __expf(x));
}
__device__ __forceinline__ float tanhfastf(float x){
  float e = __expf(2.f * x);
  return 1.f - 2.f/(e + 1.f);
}
__device__ __forceinline__ void abc_from(float pin, float draw, float braw, float craw,
    float alpha, float ginv, float& a_o, float& bu_o, float& c_o){
  float sp = softplusf(draw);
  float av = __expf(-sp * alpha);
  av = fminf(av, 1.f - 1e-4f);
  float bv = tanhfastf(braw);
  float cv = tanhfastf(craw);
  float p = av*av + cv*cv;
  float r = bv*bv;
  float q = av*bv;
  float pr = p - r;
  float disc = pr*pr + 4.f*q*q;
  float lam = 0.5f*(p + r + sqrtf(disc + 1e-12f));
  float inv = fminf(rsqrtf(lam + 1e-12f), 1.f);
  a_o = av * inv;
  c_o = cv * inv;
  bu_o = (bv * inv) * (pin * ginv);
}

// ---- fused fp32->bf16 conversion + INTERLEAVE of weight rows + sc zero-init ----
// Wcat16 row (4n+s): s=0 -> W_in[n], s=1..3 -> pn_w[(s-1)*N + n] (delta, b, c).
// => P = u @ Wcat^T has layout [t][n][4]: all 4 gate streams adjacent per n.
#define U4    2097152
#define WIN4   262144
#define PNW4   786432
#define WOUT4  262144
#define CONV_BLOCKS ((U4 + WIN4 + PNW4 + WOUT4 + 255)/256)

__global__ void k_convert_all(const float* __restrict__ u, const float* __restrict__ Win,
                              const float* __restrict__ pnw, const float* __restrict__ Wout,
                              unsigned short* __restrict__ u16, unsigned short* __restrict__ Wcat16,
                              unsigned short* __restrict__ Wout16, float* __restrict__ sc){
  if (blockIdx.x == 0 && threadIdx.x < 64) sc[threadIdx.x] = 0.f;
  long i = (long)blockIdx.x * 256 + threadIdx.x;
  const float* src; long o; size_t didx; unsigned short* dbuf;
  if (i < U4){
    src = u; o = i; dbuf = u16; didx = (size_t)o;
  } else if (i < U4+WIN4){
    o = i - U4; src = Win;
    int n = (int)(o >> 8), c4 = (int)(o & 255);
    dbuf = Wcat16; didx = (size_t)(4*n)*256 + c4;
  } else if (i < U4+WIN4+PNW4){
    o = i - (U4+WIN4); src = pnw;
    int m = (int)(o >> 8), c4 = (int)(o & 255);
    int s = (m >> 10) + 1, n = m & 1023;
    dbuf = Wcat16; didx = (size_t)(4*n + s)*256 + c4;
  } else if (i < U4+WIN4+PNW4+WOUT4){
    o = i - (U4+WIN4+PNW4); src = Wout; dbuf = Wout16; didx = (size_t)o;
  } else return;
  float4 v = ((const float4*)src)[o];
  us4 w;
  w.x = f2bf(v.x); w.y = f2bf(v.y); w.z = f2bf(v.z); w.w = f2bf(v.w);
  ((us4*)dbuf)[didx] = w;
}

__device__ __forceinline__ void load_lds16(const unsigned short* g, unsigned short* l){
  __builtin_amdgcn_global_load_lds((const __attribute__((address_space(1))) void*)g,
                                   (__attribute__((address_space(3))) void*)l, 16, 0, 0);
}

// ---- big GEMM: C[M,N] = (A[M,K] * B[N,K]^T) * (step>=0 ? inv_scale(step) : 1) ----
// 128x128 tile, proven m97-structure (89.5us P / ~23us out). Pure GEMM, no fusion.
template<int OUTBF16>
__global__ __launch_bounds__(256) void k_gemm(
    const unsigned short* __restrict__ A,
    const unsigned short* __restrict__ Bmat,
    void* __restrict__ C0,
    int M, int N, int K,
    const float* __restrict__ sc, int step)
{
  __shared__ alignas(16) unsigned short As[128*64];
  __shared__ alignas(16) unsigned short Bs[128*64];
  const int tid = threadIdx.x;
  const int wid = tid >> 6;
  const int lane = tid & 63;
  const int bn = blockIdx.x, bm = blockIdx.y;

  char* C = (char*)C0;
  float outscale = (step >= 0) ? inv_scale(sc, step) : 1.f;

  const int wr = wid >> 1, wc = wid & 1;
  const int rg = lane >> 3;
  const int cby = (lane & 7) << 4;
  const int srow0 = wid * 32;
  const int frow = lane & 15;
  const int kgrp = lane >> 4;

  const unsigned short* ap[4];
  const unsigned short* bp[4];
  unsigned short* adst[4];
  unsigned short* bdst[4];
  #pragma unroll
  for (int i = 0; i < 4; i++){
    int r = srow0 + i*8 + rg;
    int cb = cby ^ ((r & 7) << 4);
    ap[i] = A    + (size_t)(bm*128 + r)*K + (cb >> 1);
    bp[i] = Bmat + (size_t)(bn*128 + r)*K + (cb >> 1);
    adst[i] = As + (srow0 + i*8)*64;
    bdst[i] = Bs + (srow0 + i*8)*64;
  }
  int aoff[4][2], boff[4][2];
  #pragma unroll
  for (int m = 0; m < 4; m++){
    int r = wr*64 + m*16 + frow;
    #pragma unroll
    for (int kk = 0; kk < 2; kk++)
      aoff[m][kk] = r*128 + ((kk*64 + kgrp*16) ^ ((r & 7) << 4));
  }
  #pragma unroll
  for (int n2 = 0; n2 < 4; n2++){
    int r = wc*64 + n2*16 + frow;
    #pragma unroll
    for (int kk = 0; kk < 2; kk++)
      boff[n2][kk] = r*128 + ((kk*64 + kgrp*16) ^ ((r & 7) << 4));
  }

  f32x4 acc[4][4] = {};

  for (int kt = 0; kt < K; kt += 64){
    #pragma unroll
    for (int i = 0; i < 4; i++){
      load_lds16(ap[i], adst[i]);
      load_lds16(bp[i], bdst[i]);
      ap[i] += 64; bp[i] += 64;
    }
    __syncthreads();
    #pragma unroll
    for (int kk = 0; kk < 2; kk++){
      bf16x8 af[4], bfv[4];
      #pragma unroll
      for (int m = 0; m < 4; m++)
        af[m] = *(const bf16x8*)((const char*)As + aoff[m][kk]);
      #pragma unroll
      for (int n2 = 0; n2 < 4; n2++)
        bfv[n2] = *(const bf16x8*)((const char*)Bs + boff[n2][kk]);
      #pragma unroll
      for (int m = 0; m < 4; m++)
        #pragma unroll
        for (int n2 = 0; n2 < 4; n2++)
          acc[m][n2] = __builtin_amdgcn_mfma_f32_16x16x32_bf16(af[m], bfv[n2], acc[m][n2], 0, 0, 0);
    }
    __syncthreads();
  }

  const int row0 = bm*128 + wr*64;
  const int col0 = bn*128 + wc*64 + frow;
  #pragma unroll
  for (int m = 0; m < 4; m++){
    #pragma unroll
    for (int n2 = 0; n2 < 4; n2++){
      const int col = col0 + n2*16;
      const int rb = row0 + m*16 + kgrp*4;
      #pragma unroll
      for (int j = 0; j < 4; j++){
        float v = acc[m][n2][j] * outscale;
        if (OUTBF16) ((unsigned short*)C)[(size_t)(rb + j)*N + col] = f2bf(v);
        else         ((float*)C)[(size_t)(rb + j)*N + col] = v;
      }
    }
  }
}

// ---- triangular squaring-chain GEMM (C = X*X^T symmetric, upper tiles only) ----
__global__ __launch_bounds__(256) void k_sq(
    const unsigned short* __restrict__ A0, unsigned short* __restrict__ C0,
    const unsigned short* __restrict__ A1, unsigned short* __restrict__ C1,
    float* __restrict__ sc, int step)
{
  __shared__ alignas(16) unsigned short As0[64*128], Bs0[64*128];
  __shared__ alignas(16) unsigned short As1[64*128], Bs1[64*128];
  const int tid = threadIdx.x;
  const int wid = tid >> 6;
  const int lane = tid & 63;
  const int z = blockIdx.z;

  int x = blockIdx.x, bm = 0;
  while (x >= 16 - bm){ x -= 16 - bm; bm++; }
  const int bn = bm + x;

  const unsigned short* A = z ? A1 : A0;
  unsigned short* C = z ? C1 : C0;
  const size_t rs = (step == 0 && z == 0) ? 4096 : 1024;
  float outscale = 1.f;
  if (step > 0){ float t = sc[8 + (step-1)*2 + z]; outscale = 1.f/(t*t); }

  const int wr = wid >> 1, wc = wid & 1;
  const int frow = lane & 15;
  const int kgrp = lane >> 4;

  const int srl = lane >> 4;
  const int sgr = lane & 15;
  const int swzr = wid*4 + srl;
  const int scol_e = ((sgr ^ swzr) << 3);

  const size_t Arow = (size_t)bm * 64;
  const size_t Brow = (size_t)bn * 64;

  f32x4 acc[2][2] = {};

  auto stage = [&](unsigned short* as, unsigned short* bs, int t){
    const int kt = t * 128;
    #pragma unroll
    for (int i = 0; i < 4; i++){
      int r = i*16 + wid*4 + srl;
      load_lds16(A + (Arow + r)*rs + kt + scol_e, as + (i*16 + wid*4)*128);
      load_lds16(A + (Brow + r)*rs + kt + scol_e, bs + (i*16 + wid*4)*128);
    }
  };

  auto compute = [&](const unsigned short* as, const unsigned short* bs){
    #pragma unroll
    for (int ks = 0; ks < 4; ks++){
      const int kb = ks*64 + kgrp*16;
      bf16x8 af[2], bfv[2];
      #pragma unroll
      for (int m = 0; m < 2; m++){
        int r = wr*32 + m*16 + frow;
        af[m] = *(const bf16x8*)((const char*)as + r*256 + (kb ^ (frow << 4)));
      }
      #pragma unroll
      for (int n2 = 0; n2 < 2; n2++){
        int r = wc*32 + n2*16 + frow;
        bfv[n2] = *(const bf16x8*)((const char*)bs + r*256 + (kb ^ (frow << 4)));
      }
      #pragma unroll
      for (int m = 0; m < 2; m++)
        #pragma unroll
        for (int n2 = 0; n2 < 2; n2++)
          acc[m][n2] = __builtin_amdgcn_mfma_f32_16x16x32_bf16(af[m], bfv[n2], acc[m][n2], 0, 0, 0);
    }
  };

  stage(As0, Bs0, 0);
  __syncthreads();
  for (int t2 = 0; t2 < 8; t2 += 2){
    if (t2 + 1 < 8) stage(As1, Bs1, t2 + 1);
    compute(As0, Bs0);
    __syncthreads();
    if (t2 + 2 < 8) stage(As0, Bs0, t2 + 2);
    compute(As1, Bs1);
    __syncthreads();
  }

  const int row0 = bm*64 + wr*32;
  const int col0 = bn*64 + wc*32 + frow;
  float fr = 0.f;
  #pragma unroll
  for (int m = 0; m < 2; m++){
    #pragma unroll
    for (int n2 = 0; n2 < 2; n2++){
      const int col = col0 + n2*16;
      const int rb = row0 + m*16 + kgrp*4;
      us4 tw;
      #pragma unroll
      for (int j = 0; j < 4; j++){
        float v = acc[m][n2][j] * outscale;
        unsigned short h = f2bf(v);
        C[(size_t)(rb + j)*1024 + col] = h;
        tw[j] = h;
        fr += v*v;
      }
      if (bm != bn)
        *(us4*)(C + (size_t)col*1024 + rb) = tw;
    }
  }
  if (bm == bn && wr == wc){
    int j = frow - kgrp*4;
    if (j >= 0 && j < 4){
      float d = (acc[0][0][j] + acc[1][1][j]) * outscale;
      atomicAdd(&sc[8 + step*2 + z], d);
    }
  }
  if (step == SQN){
    if (bm != bn) fr *= 2.f;
    #pragma unroll
    for (int off = 32; off; off >>= 1) fr += __shfl_down(fr, off, 64);
    if (lane == 0) atomicAdd(&sc[8 + 2*(SQN+1) + z], fr);
  }
}

// ---- k_gate: per-chunk (A,S). Whole 16-row chunk batch-loaded into registers
// (16 x 16B in flight/thread) -> BW-bound. grid (NCH, 2, B_) = 1024 blocks.
__global__ __launch_bounds__(256) void k_gate(
    const unsigned short* __restrict__ P,
    const float* __restrict__ alog, const float* __restrict__ dbias,
    const float* __restrict__ pnb, const float* __restrict__ lgam,
    const float* __restrict__ sc,
    float* __restrict__ Asum, float* __restrict__ Ssum)
{
  const int tid = threadIdx.x;
  const int n0 = blockIdx.y*512 + tid*2;
  const int ch = blockIdx.x, b = blockIdx.z;

  const unsigned short* Pr = P + (size_t)(b*T_ + ch*TC)*4096 + 4*n0;
  bf16x8 e[TC];
  #pragma unroll
  for (int i = 0; i < TC; i++)
    e[i] = *(const bf16x8*)(Pr + (size_t)i*4096);

  const float ginv = __expf(lgam[0]) * inv_scale(sc, 0);
  float alpha[2], bd[2], bb[2], bc[2], A[2] = {1.f,1.f}, S[2] = {0.f,0.f};
  #pragma unroll
  for (int j = 0; j < 2; j++){
    alpha[j] = softplusf(alog[n0+j]);
    bd[j] = dbias[n0+j] + pnb[n0+j];
    bb[j] = pnb[N_ + n0+j];
    bc[j] = pnb[2*N_ + n0+j];
  }

  #pragma unroll
  for (int i = 0; i < TC; i++){
    #pragma unroll
    for (int j = 0; j < 2; j++){
      const int o = j*4;
      float a, bu, c;
      abc_from(bf2f((unsigned short)e[i][o]),   bf2f((unsigned short)e[i][o+1]) + bd[j],
               bf2f((unsigned short)e[i][o+2]) + bb[j], bf2f((unsigned short)e[i][o+3]) + bc[j],
               alpha[j], ginv, a, bu, c);
      S[j] = fmaf(a, S[j], bu);
      A[j] *= a;
    }
  }
  const size_t idx = (size_t)(b*NCH + ch)*N_ + n0;
  *(float2*)(Asum + idx) = make_float2(A[0], A[1]);
  *(float2*)(Ssum + idx) = make_float2(S[0], S[1]);
}

// ---- k_scan3: prefix over Asum/Ssum (pass2 fused, 4-deep load pipeline) +
// gate recompute from register-batched P chunk + y_hat emit. grid (NCH, 2, B_).
__global__ __launch_bounds__(256) void k_scan3(
    const unsigned short* __restrict__ P,
    const float* __restrict__ alog, const float* __restrict__ dbias,
    const float* __restrict__ pnb, const float* __restrict__ lgam,
    const float* __restrict__ sc,
    const float* __restrict__ Asum, const float* __restrict__ Ssum,
    const float* __restrict__ z0, unsigned short* __restrict__ yh)
{
  const int tid = threadIdx.x;
  const int n0 = blockIdx.y*512 + tid*2;
  const int ch = blockIdx.x, b = blockIdx.z;

  const unsigned short* Pr = P + (size_t)(b*T_ + ch*TC)*4096 + 4*n0;
  bf16x8 e[TC];
  #pragma unroll
  for (int i = 0; i < TC; i++)
    e[i] = *(const bf16x8*)(Pr + (size_t)i*4096);

  const float ginv = __expf(lgam[0]) * inv_scale(sc, 0);
  float alpha[2], bd[2], bb[2], bc[2], z[2];
  #pragma unroll
  for (int j = 0; j < 2; j++){
    alpha[j] = softplusf(alog[n0+j]);
    bd[j] = dbias[n0+j] + pnb[n0+j];
    bb[j] = pnb[N_ + n0+j];
    bc[j] = pnb[2*N_ + n0+j];
    z[j] = z0[b*N_ + n0 + j];
  }

  // prefix over chunks < ch: unroll-4, loads batched ahead of the fma chain
  const float* Ap = Asum + (size_t)b*NCH*N_ + n0;
  const float* Sp = Ssum + (size_t)b*NCH*N_ + n0;
  int c2 = 0;
  for (; c2 + 4 <= ch; c2 += 4){
    float2 Av[4], Sv[4];
    #pragma unroll
    for (int k = 0; k < 4; k++){
      Av[k] = *(const float2*)(Ap + (size_t)(c2+k)*N_);
      Sv[k] = *(const float2*)(Sp + (size_t)(c2+k)*N_);
    }
    #pragma unroll
    for (int k = 0; k < 4; k++){
      z[0] = fmaf(Av[k].x, z[0], Sv[k].x);
      z[1] = fmaf(Av[k].y, z[1], Sv[k].y);
    }
  }
  for (; c2 < ch; c2++){
    float2 Av = *(const float2*)(Ap + (size_t)c2*N_);
    float2 Sv = *(const float2*)(Sp + (size_t)c2*N_);
    z[0] = fmaf(Av.x, z[0], Sv.x);
    z[1] = fmaf(Av.y, z[1], Sv.y);
  }

  unsigned short* Y = yh + (size_t)(b*T_ + ch*TC)*N_ + n0;
  #pragma unroll
  for (int i = 0; i < TC; i++){
    unsigned int ow = 0;
    #pragma unroll
    for (int j = 0; j < 2; j++){
      const int o = j*4;
      float a, bu, c;
      abc_from(bf2f((unsigned short)e[i][o]),   bf2f((unsigned short)e[i][o+1]) + bd[j],
               bf2f((unsigned short)e[i][o+2]) + bb[j], bf2f((unsigned short)e[i][o+3]) + bc[j],
               alpha[j], ginv, a, bu, c);
      float yv = c * z[j];
      z[j] = fmaf(a, z[j], bu);
      ow |= ((unsigned int)f2bf(yv)) << (16*j);
    }
    *(unsigned int*)Y = ow;
    Y += N_;
  }
}

extern "C" void kernel_launch(void* const* d_in, const int* in_sizes, int n_in,
                              void* d_out, int out_size, void* d_ws, size_t ws_size,
                              hipStream_t stream)
{
  const float* u    = (const float*)d_in[0];
  const float* z0   = (const float*)d_in[1];
  const float* Win  = (const float*)d_in[2];
  const float* Wout = (const float*)d_in[3];
  const float* pnw  = (const float*)d_in[4];
  const float* pnb  = (const float*)d_in[5];
  const float* alog = (const float*)d_in[6];
  const float* dbias= (const float*)d_in[7];
  const float* lgam = (const float*)d_in[8];

  char* ws = (char*)d_ws;
  size_t off = 0;
  auto alloc = [&](size_t bytes) -> void* {
    void* p = ws + off;
    off += (bytes + 255) & ~(size_t)255;
    return p;
  };
  float*          sc     = (float*)         alloc(1024);
  unsigned short* u16    = (unsigned short*)alloc((size_t)8192*1024*2);
  unsigned short* Wcat16 = (unsigned short*)alloc((size_t)4096*1024*2);
  unsigned short* Wout16 = (unsigned short*)alloc((size_t)1024*1024*2);
  unsigned short* P16    = (unsigned short*)alloc((size_t)8192*4096*2);
  unsigned short* yh16   = (unsigned short*)alloc((size_t)8192*1024*2);
  unsigned short* Hping  = (unsigned short*)alloc((size_t)2*1024*1024*2);
  unsigned short* Hpong  = (unsigned short*)alloc((size_t)2*1024*1024*2);
  float*          Asum   = (float*)alloc((size_t)B_*NCH*N_*4);
  float*          Ssum   = (float*)alloc((size_t)B_*NCH*N_*4);

  k_convert_all<<<CONV_BLOCKS, 256, 0, stream>>>(u, Win, pnw, Wout, u16, Wcat16, Wout16, sc);

  // spectral-norm chains: gram (step 0) + SQN squarings (triangular); frob fused in last step
  dim3 gsq(136, 1, 2);
  k_sq<<<gsq, 256, 0, stream>>>(Wcat16, Hping, Wout16, Hping + (size_t)1024*1024, sc, 0);
  unsigned short* hin = Hping;
  unsigned short* hout = Hpong;
  for (int s = 1; s <= SQN; s++){
    k_sq<<<gsq, 256, 0, stream>>>(hin, hout, hin + (size_t)1024*1024, hout + (size_t)1024*1024, sc, s);
    unsigned short* t = hin; hin = hout; hout = t;
  }

  // P = u @ Wcat^T  (bf16 out, interleaved [t][n][4]; inv_scale applied in gate/scan)
  dim3 g1(4096/128, 8192/128);
  k_gemm<1><<<g1, 256, 0, stream>>>(u16, Wcat16, P16, 8192, 4096, 1024, sc, -1);

  // per-chunk (A,S)
  dim3 gg(NCH, 2, B_);
  k_gate<<<gg, 256, 0, stream>>>(P16, alog, dbias, pnb, lgam, sc, Asum, Ssum);

  // fused pass2+pass3: prefix + gate recompute + y_hat
  k_scan3<<<gg, 256, 0, stream>>>(P16, alog, dbias, pnb, lgam, sc, Asum, Ssum, z0, yh16);

  // y = (y_hat @ W_out^T) * inv_scale(sc,1)  (fp32 out)
  dim3 g2(1024/128, 8192/128);
  k_gemm<0><<<g2, 256, 0, stream>>>(yh16, Wout16, d_out, 8192, 1024, 1024, sc, 1);
}

// Round 15
// 283.865 us; speedup vs baseline: 1.3893x; 1.2116x over previous
//
#include <hip/hip_runtime.h>
#include <stdint.h>

#define B_ 4
#define T_ 2048
#define D_ 1024
#define N_ 1024
#define TC 16
#define NCH (T_/TC)
#define SQN 6   // squaring GEMMs after gram; +1 effective doubling via fused Frobenius

typedef __attribute__((ext_vector_type(4))) float f32x4;
typedef __attribute__((ext_vector_type(8))) short bf16x8;
typedef __attribute__((ext_vector_type(4))) unsigned short us4;

__device__ __forceinline__ unsigned short f2bf(float f){
  unsigned int u = __float_as_uint(f);
  return (unsigned short)((u + 0x7fffu + ((u >> 16) & 1u)) >> 16);
}
__device__ __forceinline__ float bf2f(unsigned short h){
  return __uint_as_float(((unsigned int)h) << 16);
}

// inverse spectral scale from trace chain (z=0: W_in, z=1: W_out)
__device__ __forceinline__ float inv_scale(const float* __restrict__ sc, int z){
  float ll = 0.f, w = 1.f, t = 1.f;
  #pragma unroll
  for (int i = 0; i <= SQN; i++){
    t = sc[8 + 2*i + z];
    ll += w * __logf(t);
    w *= 0.5f;
  }
  float F = sc[8 + 2*(SQN+1) + z];
  ll += w * __logf(F / (t*t));
  float sig = fmaxf(__expf(0.5f * ll), 1e-5f);
  return 1.f / fmaxf(sig, 1.f);
}

__device__ __forceinline__ float softplusf(float x){
  return (x > 0.f) ? (x + __logf(1.f + __expf(-x))) : __logf(1.f + __expf(x));
}
__device__ __forceinline__ float tanhfastf(float x){
  float e = __expf(2.f * x);
  return 1.f - 2.f/(e + 1.f);
}

// ---- fused fp32->bf16 conversion + INTERLEAVE of weight rows + sc zero-init ----
// Wcat16 row (4n+s): s=0 -> W_in[n], s=1..3 -> pn_w[(s-1)*N + n] (delta, b, c).
#define U4    2097152
#define WIN4   262144
#define PNW4   786432
#define WOUT4  262144
#define CONV_BLOCKS ((U4 + WIN4 + PNW4 + WOUT4 + 255)/256)

__global__ void k_convert_all(const float* __restrict__ u, const float* __restrict__ Win,
                              const float* __restrict__ pnw, const float* __restrict__ Wout,
                              unsigned short* __restrict__ u16, unsigned short* __restrict__ Wcat16,
                              unsigned short* __restrict__ Wout16, float* __restrict__ sc){
  if (blockIdx.x == 0 && threadIdx.x < 64) sc[threadIdx.x] = 0.f;
  long i = (long)blockIdx.x * 256 + threadIdx.x;
  const float* src; long o; size_t didx; unsigned short* dbuf;
  if (i < U4){
    src = u; o = i; dbuf = u16; didx = (size_t)o;
  } else if (i < U4+WIN4){
    o = i - U4; src = Win;
    int n = (int)(o >> 8), c4 = (int)(o & 255);
    dbuf = Wcat16; didx = (size_t)(4*n)*256 + c4;
  } else if (i < U4+WIN4+PNW4){
    o = i - (U4+WIN4); src = pnw;
    int m = (int)(o >> 8), c4 = (int)(o & 255);
    int s = (m >> 10) + 1, n = m & 1023;
    dbuf = Wcat16; didx = (size_t)(4*n + s)*256 + c4;
  } else if (i < U4+WIN4+PNW4+WOUT4){
    o = i - (U4+WIN4+PNW4); src = Wout; dbuf = Wout16; didx = (size_t)o;
  } else return;
  float4 v = ((const float4*)src)[o];
  us4 w;
  w.x = f2bf(v.x); w.y = f2bf(v.y); w.z = f2bf(v.z); w.w = f2bf(v.w);
  ((us4*)dbuf)[didx] = w;
}

__device__ __forceinline__ void load_lds16(const unsigned short* g, unsigned short* l){
  __builtin_amdgcn_global_load_lds((const __attribute__((address_space(1))) void*)g,
                                   (__attribute__((address_space(3))) void*)l, 16, 0, 0);
}

// ==== gated P-GEMM v3: SWAPPED MFMA OPERANDS so each lane's acc f32x4 holds the
// 4 gate streams (pin,draw,braw,craw) of one (n,t). Gate math runs directly on
// the accumulator — no transpose, no LDS round-trip, no shuffles. Emits
// G1[t][n] = packed(a,c) bf16 and G2[t][n] = bu fp32. Chunk reduce in k_scanA.
__global__ __launch_bounds__(256) void k_pgemm(
    const unsigned short* __restrict__ A,      // u16 [8192][1024]
    const unsigned short* __restrict__ Bmat,   // Wcat16 [4096][1024] interleaved
    const float* __restrict__ alog, const float* __restrict__ dbias,
    const float* __restrict__ pnb, const float* __restrict__ lgam,
    const float* __restrict__ sc,
    unsigned int* __restrict__ G1,
    float* __restrict__ G2)
{
  __shared__ alignas(16) unsigned short As[128*64];
  __shared__ alignas(16) unsigned short Bs[128*64];
  const int tid = threadIdx.x;
  const int wid = tid >> 6;
  const int lane = tid & 63;
  const int bn = blockIdx.x, bm = blockIdx.y;
  const int K = 1024;

  const int wr = wid >> 1, wc = wid & 1;
  const int rg = lane >> 3;
  const int cby = (lane & 7) << 4;
  const int srow0 = wid * 32;
  const int frow = lane & 15;
  const int kgrp = lane >> 4;

  const unsigned short* ap[4];
  const unsigned short* bp[4];
  unsigned short* adst[4];
  unsigned short* bdst[4];
  #pragma unroll
  for (int i = 0; i < 4; i++){
    int r = srow0 + i*8 + rg;
    int cb = cby ^ ((r & 7) << 4);
    ap[i] = A    + (size_t)(bm*128 + r)*K + (cb >> 1);
    bp[i] = Bmat + (size_t)(bn*128 + r)*K + (cb >> 1);
    adst[i] = As + (srow0 + i*8)*64;
    bdst[i] = Bs + (srow0 + i*8)*64;
  }
  int aoff[4][2], boff[4][2];
  #pragma unroll
  for (int m = 0; m < 4; m++){
    int r = wr*64 + m*16 + frow;
    #pragma unroll
    for (int kk = 0; kk < 2; kk++)
      aoff[m][kk] = r*128 + ((kk*64 + kgrp*16) ^ ((r & 7) << 4));
  }
  #pragma unroll
  for (int n2 = 0; n2 < 4; n2++){
    int r = wc*64 + n2*16 + frow;
    #pragma unroll
    for (int kk = 0; kk < 2; kk++)
      boff[n2][kk] = r*128 + ((kk*64 + kgrp*16) ^ ((r & 7) << 4));
  }

  f32x4 acc[4][4] = {};

  for (int kt = 0; kt < K; kt += 64){
    #pragma unroll
    for (int i = 0; i < 4; i++){
      load_lds16(ap[i], adst[i]);
      load_lds16(bp[i], bdst[i]);
      ap[i] += 64; bp[i] += 64;
    }
    __syncthreads();
    #pragma unroll
    for (int kk = 0; kk < 2; kk++){
      bf16x8 af[4], bfv[4];
      #pragma unroll
      for (int m = 0; m < 4; m++)
        af[m] = *(const bf16x8*)((const char*)As + aoff[m][kk]);
      #pragma unroll
      for (int n2 = 0; n2 < 4; n2++)
        bfv[n2] = *(const bf16x8*)((const char*)Bs + boff[n2][kk]);
      // swapped operands: D-row <-> W-row (streams), D-col <-> u-row (t)
      #pragma unroll
      for (int m = 0; m < 4; m++)
        #pragma unroll
        for (int n2 = 0; n2 < 4; n2++)
          acc[m][n2] = __builtin_amdgcn_mfma_f32_16x16x32_bf16(bfv[n2], af[m], acc[m][n2], 0, 0, 0);
    }
    __syncthreads();
  }

  // ===== per-lane gated epilogue (no cross-lane ops) =====
  const float ginv = __expf(lgam[0]) * inv_scale(sc, 0);
  float alpha[4], bd[4], bb[4], bc[4];
  #pragma unroll
  for (int nw = 0; nw < 4; nw++){
    int n = bn*32 + wc*16 + nw*4 + kgrp;
    alpha[nw] = softplusf(alog[n]);
    bd[nw] = dbias[n] + pnb[n];
    bb[nw] = pnb[N_ + n];
    bc[nw] = pnb[2*N_ + n];
  }
  const int t0 = bm*128 + wr*64 + frow;
  #pragma unroll
  for (int mu = 0; mu < 4; mu++){
    const size_t rowb = (size_t)(t0 + mu*16) * N_;
    #pragma unroll
    for (int nw = 0; nw < 4; nw++){
      const int n = bn*32 + wc*16 + nw*4 + kgrp;
      f32x4 v = acc[mu][nw];
      // a = exp(-alpha*softplus(draw)) via branchless power form
      float lp = __logf(1.f + __expf(v[1] + bd[nw]));
      float av = fminf(__expf(-alpha[nw]*lp), 1.f - 1e-4f);
      float bv = tanhfastf(v[2] + bb[nw]);
      float cv = tanhfastf(v[3] + bc[nw]);
      float p = av*av + cv*cv;
      float r = bv*bv;
      float q = av*bv;
      float pr = p - r;
      float disc = pr*pr + 4.f*q*q;
      float lam = 0.5f*(p + r + sqrtf(disc + 1e-12f));
      float inv = fminf(rsqrtf(lam + 1e-12f), 1.f);
      float a = av * inv;
      float c = cv * inv;
      float bu = (bv * inv) * (v[0] * ginv);
      G1[rowb + n] = (unsigned int)f2bf(a) | ((unsigned int)f2bf(c) << 16);
      G2[rowb + n] = bu;
    }
  }
}

// ---- out-GEMM: C[M,N] = (A[M,K] * B[N,K]^T) * inv_scale(step)  (128^2, m97) ----
template<int OUTBF16>
__global__ __launch_bounds__(256) void k_gemm(
    const unsigned short* __restrict__ A,
    const unsigned short* __restrict__ Bmat,
    void* __restrict__ C0,
    int M, int N, int K,
    const float* __restrict__ sc, int step)
{
  __shared__ alignas(16) unsigned short As[128*64];
  __shared__ alignas(16) unsigned short Bs[128*64];
  const int tid = threadIdx.x;
  const int wid = tid >> 6;
  const int lane = tid & 63;
  const int bn = blockIdx.x, bm = blockIdx.y;

  char* C = (char*)C0;
  float outscale = (step >= 0) ? inv_scale(sc, step) : 1.f;

  const int wr = wid >> 1, wc = wid & 1;
  const int rg = lane >> 3;
  const int cby = (lane & 7) << 4;
  const int srow0 = wid * 32;
  const int frow = lane & 15;
  const int kgrp = lane >> 4;

  const unsigned short* ap[4];
  const unsigned short* bp[4];
  unsigned short* adst[4];
  unsigned short* bdst[4];
  #pragma unroll
  for (int i = 0; i < 4; i++){
    int r = srow0 + i*8 + rg;
    int cb = cby ^ ((r & 7) << 4);
    ap[i] = A    + (size_t)(bm*128 + r)*K + (cb >> 1);
    bp[i] = Bmat + (size_t)(bn*128 + r)*K + (cb >> 1);
    adst[i] = As + (srow0 + i*8)*64;
    bdst[i] = Bs + (srow0 + i*8)*64;
  }
  int aoff[4][2], boff[4][2];
  #pragma unroll
  for (int m = 0; m < 4; m++){
    int r = wr*64 + m*16 + frow;
    #pragma unroll
    for (int kk = 0; kk < 2; kk++)
      aoff[m][kk] = r*128 + ((kk*64 + kgrp*16) ^ ((r & 7) << 4));
  }
  #pragma unroll
  for (int n2 = 0; n2 < 4; n2++){
    int r = wc*64 + n2*16 + frow;
    #pragma unroll
    for (int kk = 0; kk < 2; kk++)
      boff[n2][kk] = r*128 + ((kk*64 + kgrp*16) ^ ((r & 7) << 4));
  }

  f32x4 acc[4][4] = {};

  for (int kt = 0; kt < K; kt += 64){
    #pragma unroll
    for (int i = 0; i < 4; i++){
      load_lds16(ap[i], adst[i]);
      load_lds16(bp[i], bdst[i]);
      ap[i] += 64; bp[i] += 64;
    }
    __syncthreads();
    #pragma unroll
    for (int kk = 0; kk < 2; kk++){
      bf16x8 af[4], bfv[4];
      #pragma unroll
      for (int m = 0; m < 4; m++)
        af[m] = *(const bf16x8*)((const char*)As + aoff[m][kk]);
      #pragma unroll
      for (int n2 = 0; n2 < 4; n2++)
        bfv[n2] = *(const bf16x8*)((const char*)Bs + boff[n2][kk]);
      #pragma unroll
      for (int m = 0; m < 4; m++)
        #pragma unroll
        for (int n2 = 0; n2 < 4; n2++)
          acc[m][n2] = __builtin_amdgcn_mfma_f32_16x16x32_bf16(af[m], bfv[n2], acc[m][n2], 0, 0, 0);
    }
    __syncthreads();
  }

  const int row0 = bm*128 + wr*64;
  const int col0 = bn*128 + wc*64 + frow;
  #pragma unroll
  for (int m = 0; m < 4; m++){
    #pragma unroll
    for (int n2 = 0; n2 < 4; n2++){
      const int col = col0 + n2*16;
      const int rb = row0 + m*16 + kgrp*4;
      #pragma unroll
      for (int j = 0; j < 4; j++){
        float v = acc[m][n2][j] * outscale;
        if (OUTBF16) ((unsigned short*)C)[(size_t)(rb + j)*N + col] = f2bf(v);
        else         ((float*)C)[(size_t)(rb + j)*N + col] = v;
      }
    }
  }
}

// ---- triangular squaring-chain GEMM (C = X*X^T symmetric, upper tiles only) ----
__global__ __launch_bounds__(256) void k_sq(
    const unsigned short* __restrict__ A0, unsigned short* __restrict__ C0,
    const unsigned short* __restrict__ A1, unsigned short* __restrict__ C1,
    float* __restrict__ sc, int step)
{
  __shared__ alignas(16) unsigned short As0[64*128], Bs0[64*128];
  __shared__ alignas(16) unsigned short As1[64*128], Bs1[64*128];
  const int tid = threadIdx.x;
  const int wid = tid >> 6;
  const int lane = tid & 63;
  const int z = blockIdx.z;

  int x = blockIdx.x, bm = 0;
  while (x >= 16 - bm){ x -= 16 - bm; bm++; }
  const int bn = bm + x;

  const unsigned short* A = z ? A1 : A0;
  unsigned short* C = z ? C1 : C0;
  const size_t rs = (step == 0 && z == 0) ? 4096 : 1024;
  float outscale = 1.f;
  if (step > 0){ float t = sc[8 + (step-1)*2 + z]; outscale = 1.f/(t*t); }

  const int wr = wid >> 1, wc = wid & 1;
  const int frow = lane & 15;
  const int kgrp = lane >> 4;

  const int srl = lane >> 4;
  const int sgr = lane & 15;
  const int swzr = wid*4 + srl;
  const int scol_e = ((sgr ^ swzr) << 3);

  const size_t Arow = (size_t)bm * 64;
  const size_t Brow = (size_t)bn * 64;

  f32x4 acc[2][2] = {};

  auto stage = [&](unsigned short* as, unsigned short* bs, int t){
    const int kt = t * 128;
    #pragma unroll
    for (int i = 0; i < 4; i++){
      int r = i*16 + wid*4 + srl;
      load_lds16(A + (Arow + r)*rs + kt + scol_e, as + (i*16 + wid*4)*128);
      load_lds16(A + (Brow + r)*rs + kt + scol_e, bs + (i*16 + wid*4)*128);
    }
  };

  auto compute = [&](const unsigned short* as, const unsigned short* bs){
    #pragma unroll
    for (int ks = 0; ks < 4; ks++){
      const int kb = ks*64 + kgrp*16;
      bf16x8 af[2], bfv[2];
      #pragma unroll
      for (int m = 0; m < 2; m++){
        int r = wr*32 + m*16 + frow;
        af[m] = *(const bf16x8*)((const char*)as + r*256 + (kb ^ (frow << 4)));
      }
      #pragma unroll
      for (int n2 = 0; n2 < 2; n2++){
        int r = wc*32 + n2*16 + frow;
        bfv[n2] = *(const bf16x8*)((const char*)bs + r*256 + (kb ^ (frow << 4)));
      }
      #pragma unroll
      for (int m = 0; m < 2; m++)
        #pragma unroll
        for (int n2 = 0; n2 < 2; n2++)
          acc[m][n2] = __builtin_amdgcn_mfma_f32_16x16x32_bf16(af[m], bfv[n2], acc[m][n2], 0, 0, 0);
    }
  };

  stage(As0, Bs0, 0);
  __syncthreads();
  for (int t2 = 0; t2 < 8; t2 += 2){
    if (t2 + 1 < 8) stage(As1, Bs1, t2 + 1);
    compute(As0, Bs0);
    __syncthreads();
    if (t2 + 2 < 8) stage(As0, Bs0, t2 + 2);
    compute(As1, Bs1);
    __syncthreads();
  }

  const int row0 = bm*64 + wr*32;
  const int col0 = bn*64 + wc*32 + frow;
  float fr = 0.f;
  #pragma unroll
  for (int m = 0; m < 2; m++){
    #pragma unroll
    for (int n2 = 0; n2 < 2; n2++){
      const int col = col0 + n2*16;
      const int rb = row0 + m*16 + kgrp*4;
      us4 tw;
      #pragma unroll
      for (int j = 0; j < 4; j++){
        float v = acc[m][n2][j] * outscale;
        unsigned short h = f2bf(v);
        C[(size_t)(rb + j)*1024 + col] = h;
        tw[j] = h;
        fr += v*v;
      }
      if (bm != bn)
        *(us4*)(C + (size_t)col*1024 + rb) = tw;
    }
  }
  if (bm == bn && wr == wc){
    int j = frow - kgrp*4;
    if (j >= 0 && j < 4){
      float d = (acc[0][0][j] + acc[1][1][j]) * outscale;
      atomicAdd(&sc[8 + step*2 + z], d);
    }
  }
  if (step == SQN){
    if (bm != bn) fr *= 2.f;
    #pragma unroll
    for (int off = 32; off; off >>= 1) fr += __shfl_down(fr, off, 64);
    if (lane == 0) atomicAdd(&sc[8 + 2*(SQN+1) + z], fr);
  }
}

// ---- k_scanA: per-chunk (A,S) from G1/G2 — pure fma chains, no trans math ----
// grid (NCH, 2, B_); thread owns 2 n's; chunk = 16 t rows.
__global__ __launch_bounds__(256) void k_scanA(
    const unsigned int* __restrict__ G1, const float* __restrict__ G2,
    float* __restrict__ Asum, float* __restrict__ Ssum)
{
  const int tid = threadIdx.x;
  const int n0 = blockIdx.y*512 + tid*2;
  const int ch = blockIdx.x, b = blockIdx.z;
  const size_t base = (size_t)(b*T_ + ch*TC)*N_ + n0;

  uint2 g1[TC]; float2 g2[TC];
  #pragma unroll
  for (int i = 0; i < TC; i++){
    g1[i] = *(const uint2*)(G1 + base + (size_t)i*N_);
    g2[i] = *(const float2*)(G2 + base + (size_t)i*N_);
  }
  float A0 = 1.f, A1 = 1.f, S0 = 0.f, S1 = 0.f;
  #pragma unroll
  for (int i = 0; i < TC; i++){
    float a0 = bf2f((unsigned short)(g1[i].x & 0xffffu));
    float a1 = bf2f((unsigned short)(g1[i].y & 0xffffu));
    S0 = fmaf(a0, S0, g2[i].x); A0 *= a0;
    S1 = fmaf(a1, S1, g2[i].y); A1 *= a1;
  }
  const size_t idx = (size_t)(b*NCH + ch)*N_ + n0;
  *(float2*)(Asum + idx) = make_float2(A0, A1);
  *(float2*)(Ssum + idx) = make_float2(S0, S1);
}

// ---- k_scanB: self prefix over Asum/Ssum + y_hat emit from G1/G2 ----
// grid (NCH, B_); thread owns 4 n's (proven-fast R11 structure).
__global__ __launch_bounds__(256) void k_scanB(
    const unsigned int* __restrict__ G1, const float* __restrict__ G2,
    const float* __restrict__ Asum, const float* __restrict__ Ssum,
    const float* __restrict__ z0, unsigned short* __restrict__ yh)
{
  const int tid = threadIdx.x;
  const int n0 = tid*4;
  const int ch = blockIdx.x, b = blockIdx.y;
  float z[4];
  #pragma unroll
  for (int j = 0; j < 4; j++) z[j] = z0[b*N_ + n0 + j];
  for (int c2 = 0; c2 < ch; c2++){
    const size_t idx = (size_t)(b*NCH + c2)*N_ + n0;
    float4 Av = *(const float4*)(Asum + idx);
    float4 Sv = *(const float4*)(Ssum + idx);
    z[0] = fmaf(Av.x, z[0], Sv.x);
    z[1] = fmaf(Av.y, z[1], Sv.y);
    z[2] = fmaf(Av.z, z[2], Sv.z);
    z[3] = fmaf(Av.w, z[3], Sv.w);
  }
  const size_t base = (size_t)(b*T_ + ch*TC)*N_ + n0;
  const unsigned int* g1 = G1 + base;
  const float* g2 = G2 + base;
  unsigned short* Y = yh + base;
  #pragma unroll 4
  for (int i = 0; i < TC; i++){
    uint4 pac = *(const uint4*)g1;
    float4 bu = *(const float4*)g2;
    us4 ow;
    #pragma unroll
    for (int j = 0; j < 4; j++){
      unsigned int p = j==0 ? pac.x : j==1 ? pac.y : j==2 ? pac.z : pac.w;
      float buj     = j==0 ? bu.x  : j==1 ? bu.y  : j==2 ? bu.z  : bu.w;
      float a = bf2f((unsigned short)(p & 0xffffu));
      float c = bf2f((unsigned short)(p >> 16));
      float yv = c * z[j];
      z[j] = fmaf(a, z[j], buj);
      ow[j] = f2bf(yv);
    }
    *(us4*)Y = ow;
    g1 += N_; g2 += N_; Y += N_;
  }
}

extern "C" void kernel_launch(void* const* d_in, const int* in_sizes, int n_in,
                              void* d_out, int out_size, void* d_ws, size_t ws_size,
                              hipStream_t stream)
{
  const float* u    = (const float*)d_in[0];
  const float* z0   = (const float*)d_in[1];
  const float* Win  = (const float*)d_in[2];
  const float* Wout = (const float*)d_in[3];
  const float* pnw  = (const float*)d_in[4];
  const float* pnb  = (const float*)d_in[5];
  const float* alog = (const float*)d_in[6];
  const float* dbias= (const float*)d_in[7];
  const float* lgam = (const float*)d_in[8];

  char* ws = (char*)d_ws;
  size_t off = 0;
  auto alloc = [&](size_t bytes) -> void* {
    void* p = ws + off;
    off += (bytes + 255) & ~(size_t)255;
    return p;
  };
  float*          sc     = (float*)         alloc(1024);
  unsigned short* u16    = (unsigned short*)alloc((size_t)8192*1024*2);
  unsigned short* Wcat16 = (unsigned short*)alloc((size_t)4096*1024*2);
  unsigned short* Wout16 = (unsigned short*)alloc((size_t)1024*1024*2);
  unsigned int*   G1     = (unsigned int*)  alloc((size_t)8192*1024*4);
  float*          G2     = (float*)         alloc((size_t)8192*1024*4);
  unsigned short* yh16   = (unsigned short*)alloc((size_t)8192*1024*2);
  unsigned short* Hping  = (unsigned short*)alloc((size_t)2*1024*1024*2);
  unsigned short* Hpong  = (unsigned short*)alloc((size_t)2*1024*1024*2);
  float*          Asum   = (float*)alloc((size_t)B_*NCH*N_*4);
  float*          Ssum   = (float*)alloc((size_t)B_*NCH*N_*4);

  k_convert_all<<<CONV_BLOCKS, 256, 0, stream>>>(u, Win, pnw, Wout, u16, Wcat16, Wout16, sc);

  // spectral-norm chains
  dim3 gsq(136, 1, 2);
  k_sq<<<gsq, 256, 0, stream>>>(Wcat16, Hping, Wout16, Hping + (size_t)1024*1024, sc, 0);
  unsigned short* hin = Hping;
  unsigned short* hout = Hpong;
  for (int s = 1; s <= SQN; s++){
    k_sq<<<gsq, 256, 0, stream>>>(hin, hout, hin + (size_t)1024*1024, hout + (size_t)1024*1024, sc, s);
    unsigned short* t = hin; hin = hout; hout = t;
  }

  // gated P-GEMM: swapped-operand epilogue emits G1/G2 directly
  dim3 g1(4096/128, 8192/128);
  k_pgemm<<<g1, 256, 0, stream>>>(u16, Wcat16, alog, dbias, pnb, lgam, sc, G1, G2);

  // chunk (A,S) then prefix+emit
  dim3 ga(NCH, 2, B_);
  k_scanA<<<ga, 256, 0, stream>>>(G1, G2, Asum, Ssum);
  dim3 gb(NCH, B_);
  k_scanB<<<gb, 256, 0, stream>>>(G1, G2, Asum, Ssum, z0, yh16);

  // y = (y_hat @ W_out^T) * inv_scale(sc,1)  (fp32 out)
  dim3 g2(1024/128, 8192/128);
  k_gemm<0><<<g2, 256, 0, stream>>>(yh16, Wout16, d_out, 8192, 1024, 1024, sc, 1);
}

// Round 16
// 277.568 us; speedup vs baseline: 1.4208x; 1.0227x over previous
//
#include <hip/hip_runtime.h>
#include <stdint.h>

#define B_ 4
#define T_ 2048
#define D_ 1024
#define N_ 1024
#define TC 16
#define NCH (T_/TC)
#define SQN 6   // squaring GEMMs after gram; +1 effective doubling via fused Frobenius

typedef __attribute__((ext_vector_type(4))) float f32x4;
typedef __attribute__((ext_vector_type(8))) short bf16x8;
typedef __attribute__((ext_vector_type(4))) unsigned short us4;

__device__ __forceinline__ unsigned short f2bf(float f){
  unsigned int u = __float_as_uint(f);
  return (unsigned short)((u + 0x7fffu + ((u >> 16) & 1u)) >> 16);
}
__device__ __forceinline__ float bf2f(unsigned short h){
  return __uint_as_float(((unsigned int)h) << 16);
}

// inverse spectral scale from trace chain (z=0: W_in, z=1: W_out)
__device__ __forceinline__ float inv_scale(const float* __restrict__ sc, int z){
  float ll = 0.f, w = 1.f, t = 1.f;
  #pragma unroll
  for (int i = 0; i <= SQN; i++){
    t = sc[8 + 2*i + z];
    ll += w * __logf(t);
    w *= 0.5f;
  }
  float F = sc[8 + 2*(SQN+1) + z];
  ll += w * __logf(F / (t*t));
  float sig = fmaxf(__expf(0.5f * ll), 1e-5f);
  return 1.f / fmaxf(sig, 1.f);
}

__device__ __forceinline__ float softplusf(float x){
  return (x > 0.f) ? (x + __logf(1.f + __expf(-x))) : __logf(1.f + __expf(x));
}
__device__ __forceinline__ float tanhfastf(float x){
  float e = __expf(2.f * x);
  return 1.f - 2.f/(e + 1.f);
}

// ---- fused fp32->bf16 conversion + INTERLEAVE of weight rows + sc zero-init ----
// Wcat16 row (4n+s): s=0 -> W_in[n], s=1..3 -> pn_w[(s-1)*N + n] (delta, b, c).
#define U4    2097152
#define WIN4   262144
#define PNW4   786432
#define WOUT4  262144
#define CONV_BLOCKS ((U4 + WIN4 + PNW4 + WOUT4 + 255)/256)

__global__ void k_convert_all(const float* __restrict__ u, const float* __restrict__ Win,
                              const float* __restrict__ pnw, const float* __restrict__ Wout,
                              unsigned short* __restrict__ u16, unsigned short* __restrict__ Wcat16,
                              unsigned short* __restrict__ Wout16, float* __restrict__ sc){
  if (blockIdx.x == 0 && threadIdx.x < 64) sc[threadIdx.x] = 0.f;
  long i = (long)blockIdx.x * 256 + threadIdx.x;
  const float* src; long o; size_t didx; unsigned short* dbuf;
  if (i < U4){
    src = u; o = i; dbuf = u16; didx = (size_t)o;
  } else if (i < U4+WIN4){
    o = i - U4; src = Win;
    int n = (int)(o >> 8), c4 = (int)(o & 255);
    dbuf = Wcat16; didx = (size_t)(4*n)*256 + c4;
  } else if (i < U4+WIN4+PNW4){
    o = i - (U4+WIN4); src = pnw;
    int m = (int)(o >> 8), c4 = (int)(o & 255);
    int s = (m >> 10) + 1, n = m & 1023;
    dbuf = Wcat16; didx = (size_t)(4*n + s)*256 + c4;
  } else if (i < U4+WIN4+PNW4+WOUT4){
    o = i - (U4+WIN4+PNW4); src = Wout; dbuf = Wout16; didx = (size_t)o;
  } else return;
  float4 v = ((const float4*)src)[o];
  us4 w;
  w.x = f2bf(v.x); w.y = f2bf(v.y); w.z = f2bf(v.z); w.w = f2bf(v.w);
  ((us4*)dbuf)[didx] = w;
}

__device__ __forceinline__ void load_lds16(const unsigned short* g, unsigned short* l){
  __builtin_amdgcn_global_load_lds((const __attribute__((address_space(1))) void*)g,
                                   (__attribute__((address_space(3))) void*)l, 16, 0, 0);
}

// ==== gated P-GEMM: swapped MFMA operands (lane owns all 4 gate streams of one
// (n,t)); per-lane gate math on the accumulator; results staged in LDS (reusing
// the GEMM tiles) and flushed with coalesced stores (fixes 64-line store scatter).
__global__ __launch_bounds__(256) void k_pgemm(
    const unsigned short* __restrict__ A,      // u16 [8192][1024]
    const unsigned short* __restrict__ Bmat,   // Wcat16 [4096][1024] interleaved
    const float* __restrict__ alog, const float* __restrict__ dbias,
    const float* __restrict__ pnb, const float* __restrict__ lgam,
    const float* __restrict__ sc,
    unsigned int* __restrict__ G1,
    float* __restrict__ G2)
{
  __shared__ alignas(16) char smem[36864];   // GEMM: As(16K)+Bs(16K); epilogue: g1s/g2s (2x18K)
  unsigned short* As = (unsigned short*)smem;
  unsigned short* Bs = (unsigned short*)(smem + 16384);
  const int tid = threadIdx.x;
  const int wid = tid >> 6;
  const int lane = tid & 63;
  const int bn = blockIdx.x, bm = blockIdx.y;
  const int K = 1024;

  const int wr = wid >> 1, wc = wid & 1;
  const int rg = lane >> 3;
  const int cby = (lane & 7) << 4;
  const int srow0 = wid * 32;
  const int frow = lane & 15;
  const int kgrp = lane >> 4;

  const unsigned short* ap[4];
  const unsigned short* bp[4];
  unsigned short* adst[4];
  unsigned short* bdst[4];
  #pragma unroll
  for (int i = 0; i < 4; i++){
    int r = srow0 + i*8 + rg;
    int cb = cby ^ ((r & 7) << 4);
    ap[i] = A    + (size_t)(bm*128 + r)*K + (cb >> 1);
    bp[i] = Bmat + (size_t)(bn*128 + r)*K + (cb >> 1);
    adst[i] = As + (srow0 + i*8)*64;
    bdst[i] = Bs + (srow0 + i*8)*64;
  }
  int aoff[4][2], boff[4][2];
  #pragma unroll
  for (int m = 0; m < 4; m++){
    int r = wr*64 + m*16 + frow;
    #pragma unroll
    for (int kk = 0; kk < 2; kk++)
      aoff[m][kk] = r*128 + ((kk*64 + kgrp*16) ^ ((r & 7) << 4));
  }
  #pragma unroll
  for (int n2 = 0; n2 < 4; n2++){
    int r = wc*64 + n2*16 + frow;
    #pragma unroll
    for (int kk = 0; kk < 2; kk++)
      boff[n2][kk] = r*128 + ((kk*64 + kgrp*16) ^ ((r & 7) << 4));
  }

  f32x4 acc[4][4] = {};

  for (int kt = 0; kt < K; kt += 64){
    #pragma unroll
    for (int i = 0; i < 4; i++){
      load_lds16(ap[i], adst[i]);
      load_lds16(bp[i], bdst[i]);
      ap[i] += 64; bp[i] += 64;
    }
    __syncthreads();
    #pragma unroll
    for (int kk = 0; kk < 2; kk++){
      bf16x8 af[4], bfv[4];
      #pragma unroll
      for (int m = 0; m < 4; m++)
        af[m] = *(const bf16x8*)((const char*)As + aoff[m][kk]);
      #pragma unroll
      for (int n2 = 0; n2 < 4; n2++)
        bfv[n2] = *(const bf16x8*)((const char*)Bs + boff[n2][kk]);
      // swapped operands: D-row <-> W-row (streams), D-col <-> u-row (t)
      #pragma unroll
      for (int m = 0; m < 4; m++)
        #pragma unroll
        for (int n2 = 0; n2 < 4; n2++)
          acc[m][n2] = __builtin_amdgcn_mfma_f32_16x16x32_bf16(bfv[n2], af[m], acc[m][n2], 0, 0, 0);
    }
    __syncthreads();
  }

  // ===== per-lane gated epilogue; LDS-staged coalesced stores =====
  unsigned int* g1s = (unsigned int*)smem;            // [128][36] u32 (18432 B)
  float*        g2s = (float*)(smem + 18432);         // [128][36] f32

  const float ginv = __expf(lgam[0]) * inv_scale(sc, 0);
  float alpha[4], bd[4], bb[4], bc[4];
  #pragma unroll
  for (int nw = 0; nw < 4; nw++){
    int n = bn*32 + wc*16 + nw*4 + kgrp;
    alpha[nw] = softplusf(alog[n]);
    bd[nw] = dbias[n] + pnb[n];
    bb[nw] = pnb[N_ + n];
    bc[nw] = pnb[2*N_ + n];
  }
  #pragma unroll
  for (int mu = 0; mu < 4; mu++){
    const int tl = wr*64 + mu*16 + frow;
    #pragma unroll
    for (int nw = 0; nw < 4; nw++){
      const int nl = wc*16 + nw*4 + kgrp;
      f32x4 v = acc[mu][nw];
      float lp = __logf(1.f + __expf(v[1] + bd[nw]));
      float av = fminf(__expf(-alpha[nw]*lp), 1.f - 1e-4f);
      float bv = tanhfastf(v[2] + bb[nw]);
      float cv = tanhfastf(v[3] + bc[nw]);
      float p = av*av + cv*cv;
      float r = bv*bv;
      float q = av*bv;
      float pr = p - r;
      float disc = pr*pr + 4.f*q*q;
      float lam = 0.5f*(p + r + sqrtf(disc + 1e-12f));
      float inv = fminf(rsqrtf(lam + 1e-12f), 1.f);
      float a = av * inv;
      float c = cv * inv;
      float bu = (bv * inv) * (v[0] * ginv);
      g1s[tl*36 + nl] = (unsigned int)f2bf(a) | ((unsigned int)f2bf(c) << 16);
      g2s[tl*36 + nl] = bu;
    }
  }
  __syncthreads();
  // coalesced flush: 4 rounds x 256 threads cover 128 rows x 8 segs of 16B
  const size_t t0b = (size_t)bm * 128;
  const int nb = bn*32;
  #pragma unroll
  for (int r = 0; r < 4; r++){
    int flat = r*256 + tid;
    int tl = flat >> 3, seg = flat & 7;
    uint4  v1 = *(const uint4*)(g1s + tl*36 + seg*4);
    float4 v2 = *(const float4*)(g2s + tl*36 + seg*4);
    *(uint4*)(G1 + (t0b + tl)*N_ + nb + seg*4) = v1;
    *(float4*)(G2 + (t0b + tl)*N_ + nb + seg*4) = v2;
  }
}

// ---- out-GEMM: C[M,N] = (A[M,K] * B[N,K]^T) * inv_scale(step)  (128^2, m97) ----
template<int OUTBF16>
__global__ __launch_bounds__(256) void k_gemm(
    const unsigned short* __restrict__ A,
    const unsigned short* __restrict__ Bmat,
    void* __restrict__ C0,
    int M, int N, int K,
    const float* __restrict__ sc, int step)
{
  __shared__ alignas(16) unsigned short As[128*64];
  __shared__ alignas(16) unsigned short Bs[128*64];
  const int tid = threadIdx.x;
  const int wid = tid >> 6;
  const int lane = tid & 63;
  const int bn = blockIdx.x, bm = blockIdx.y;

  char* C = (char*)C0;
  float outscale = (step >= 0) ? inv_scale(sc, step) : 1.f;

  const int wr = wid >> 1, wc = wid & 1;
  const int rg = lane >> 3;
  const int cby = (lane & 7) << 4;
  const int srow0 = wid * 32;
  const int frow = lane & 15;
  const int kgrp = lane >> 4;

  const unsigned short* ap[4];
  const unsigned short* bp[4];
  unsigned short* adst[4];
  unsigned short* bdst[4];
  #pragma unroll
  for (int i = 0; i < 4; i++){
    int r = srow0 + i*8 + rg;
    int cb = cby ^ ((r & 7) << 4);
    ap[i] = A    + (size_t)(bm*128 + r)*K + (cb >> 1);
    bp[i] = Bmat + (size_t)(bn*128 + r)*K + (cb >> 1);
    adst[i] = As + (srow0 + i*8)*64;
    bdst[i] = Bs + (srow0 + i*8)*64;
  }
  int aoff[4][2], boff[4][2];
  #pragma unroll
  for (int m = 0; m < 4; m++){
    int r = wr*64 + m*16 + frow;
    #pragma unroll
    for (int kk = 0; kk < 2; kk++)
      aoff[m][kk] = r*128 + ((kk*64 + kgrp*16) ^ ((r & 7) << 4));
  }
  #pragma unroll
  for (int n2 = 0; n2 < 4; n2++){
    int r = wc*64 + n2*16 + frow;
    #pragma unroll
    for (int kk = 0; kk < 2; kk++)
      boff[n2][kk] = r*128 + ((kk*64 + kgrp*16) ^ ((r & 7) << 4));
  }

  f32x4 acc[4][4] = {};

  for (int kt = 0; kt < K; kt += 64){
    #pragma unroll
    for (int i = 0; i < 4; i++){
      load_lds16(ap[i], adst[i]);
      load_lds16(bp[i], bdst[i]);
      ap[i] += 64; bp[i] += 64;
    }
    __syncthreads();
    #pragma unroll
    for (int kk = 0; kk < 2; kk++){
      bf16x8 af[4], bfv[4];
      #pragma unroll
      for (int m = 0; m < 4; m++)
        af[m] = *(const bf16x8*)((const char*)As + aoff[m][kk]);
      #pragma unroll
      for (int n2 = 0; n2 < 4; n2++)
        bfv[n2] = *(const bf16x8*)((const char*)Bs + boff[n2][kk]);
      #pragma unroll
      for (int m = 0; m < 4; m++)
        #pragma unroll
        for (int n2 = 0; n2 < 4; n2++)
          acc[m][n2] = __builtin_amdgcn_mfma_f32_16x16x32_bf16(af[m], bfv[n2], acc[m][n2], 0, 0, 0);
    }
    __syncthreads();
  }

  const int row0 = bm*128 + wr*64;
  const int col0 = bn*128 + wc*64 + frow;
  #pragma unroll
  for (int m = 0; m < 4; m++){
    #pragma unroll
    for (int n2 = 0; n2 < 4; n2++){
      const int col = col0 + n2*16;
      const int rb = row0 + m*16 + kgrp*4;
      #pragma unroll
      for (int j = 0; j < 4; j++){
        float v = acc[m][n2][j] * outscale;
        if (OUTBF16) ((unsigned short*)C)[(size_t)(rb + j)*N + col] = f2bf(v);
        else         ((float*)C)[(size_t)(rb + j)*N + col] = v;
      }
    }
  }
}

// ---- triangular squaring-chain GEMM (C = X*X^T symmetric, upper tiles only) ----
__global__ __launch_bounds__(256) void k_sq(
    const unsigned short* __restrict__ A0, unsigned short* __restrict__ C0,
    const unsigned short* __restrict__ A1, unsigned short* __restrict__ C1,
    float* __restrict__ sc, int step)
{
  __shared__ alignas(16) unsigned short As0[64*128], Bs0[64*128];
  __shared__ alignas(16) unsigned short As1[64*128], Bs1[64*128];
  const int tid = threadIdx.x;
  const int wid = tid >> 6;
  const int lane = tid & 63;
  const int z = blockIdx.z;

  int x = blockIdx.x, bm = 0;
  while (x >= 16 - bm){ x -= 16 - bm; bm++; }
  const int bn = bm + x;

  const unsigned short* A = z ? A1 : A0;
  unsigned short* C = z ? C1 : C0;
  const size_t rs = (step == 0 && z == 0) ? 4096 : 1024;
  float outscale = 1.f;
  if (step > 0){ float t = sc[8 + (step-1)*2 + z]; outscale = 1.f/(t*t); }

  const int wr = wid >> 1, wc = wid & 1;
  const int frow = lane & 15;
  const int kgrp = lane >> 4;

  const int srl = lane >> 4;
  const int sgr = lane & 15;
  const int swzr = wid*4 + srl;
  const int scol_e = ((sgr ^ swzr) << 3);

  const size_t Arow = (size_t)bm * 64;
  const size_t Brow = (size_t)bn * 64;

  f32x4 acc[2][2] = {};

  auto stage = [&](unsigned short* as, unsigned short* bs, int t){
    const int kt = t * 128;
    #pragma unroll
    for (int i = 0; i < 4; i++){
      int r = i*16 + wid*4 + srl;
      load_lds16(A + (Arow + r)*rs + kt + scol_e, as + (i*16 + wid*4)*128);
      load_lds16(A + (Brow + r)*rs + kt + scol_e, bs + (i*16 + wid*4)*128);
    }
  };

  auto compute = [&](const unsigned short* as, const unsigned short* bs){
    #pragma unroll
    for (int ks = 0; ks < 4; ks++){
      const int kb = ks*64 + kgrp*16;
      bf16x8 af[2], bfv[2];
      #pragma unroll
      for (int m = 0; m < 2; m++){
        int r = wr*32 + m*16 + frow;
        af[m] = *(const bf16x8*)((const char*)as + r*256 + (kb ^ (frow << 4)));
      }
      #pragma unroll
      for (int n2 = 0; n2 < 2; n2++){
        int r = wc*32 + n2*16 + frow;
        bfv[n2] = *(const bf16x8*)((const char*)bs + r*256 + (kb ^ (frow << 4)));
      }
      #pragma unroll
      for (int m = 0; m < 2; m++)
        #pragma unroll
        for (int n2 = 0; n2 < 2; n2++)
          acc[m][n2] = __builtin_amdgcn_mfma_f32_16x16x32_bf16(af[m], bfv[n2], acc[m][n2], 0, 0, 0);
    }
  };

  stage(As0, Bs0, 0);
  __syncthreads();
  for (int t2 = 0; t2 < 8; t2 += 2){
    if (t2 + 1 < 8) stage(As1, Bs1, t2 + 1);
    compute(As0, Bs0);
    __syncthreads();
    if (t2 + 2 < 8) stage(As0, Bs0, t2 + 2);
    compute(As1, Bs1);
    __syncthreads();
  }

  const int row0 = bm*64 + wr*32;
  const int col0 = bn*64 + wc*32 + frow;
  float fr = 0.f;
  #pragma unroll
  for (int m = 0; m < 2; m++){
    #pragma unroll
    for (int n2 = 0; n2 < 2; n2++){
      const int col = col0 + n2*16;
      const int rb = row0 + m*16 + kgrp*4;
      us4 tw;
      #pragma unroll
      for (int j = 0; j < 4; j++){
        float v = acc[m][n2][j] * outscale;
        unsigned short h = f2bf(v);
        C[(size_t)(rb + j)*1024 + col] = h;
        tw[j] = h;
        fr += v*v;
      }
      if (bm != bn)
        *(us4*)(C + (size_t)col*1024 + rb) = tw;
    }
  }
  if (bm == bn && wr == wc){
    int j = frow - kgrp*4;
    if (j >= 0 && j < 4){
      float d = (acc[0][0][j] + acc[1][1][j]) * outscale;
      atomicAdd(&sc[8 + step*2 + z], d);
    }
  }
  if (step == SQN){
    if (bm != bn) fr *= 2.f;
    #pragma unroll
    for (int off = 32; off; off >>= 1) fr += __shfl_down(fr, off, 64);
    if (lane == 0) atomicAdd(&sc[8 + 2*(SQN+1) + z], fr);
  }
}

// ---- k_scanA: per-chunk (A,S) from G1/G2 — pure fma chains ----
__global__ __launch_bounds__(256) void k_scanA(
    const unsigned int* __restrict__ G1, const float* __restrict__ G2,
    float* __restrict__ Asum, float* __restrict__ Ssum)
{
  const int tid = threadIdx.x;
  const int n0 = blockIdx.y*512 + tid*2;
  const int ch = blockIdx.x, b = blockIdx.z;
  const size_t base = (size_t)(b*T_ + ch*TC)*N_ + n0;

  uint2 g1[TC]; float2 g2[TC];
  #pragma unroll
  for (int i = 0; i < TC; i++){
    g1[i] = *(const uint2*)(G1 + base + (size_t)i*N_);
    g2[i] = *(const float2*)(G2 + base + (size_t)i*N_);
  }
  float A0 = 1.f, A1 = 1.f, S0 = 0.f, S1 = 0.f;
  #pragma unroll
  for (int i = 0; i < TC; i++){
    float a0 = bf2f((unsigned short)(g1[i].x & 0xffffu));
    float a1 = bf2f((unsigned short)(g1[i].y & 0xffffu));
    S0 = fmaf(a0, S0, g2[i].x); A0 *= a0;
    S1 = fmaf(a1, S1, g2[i].y); A1 *= a1;
  }
  const size_t idx = (size_t)(b*NCH + ch)*N_ + n0;
  *(float2*)(Asum + idx) = make_float2(A0, A1);
  *(float2*)(Ssum + idx) = make_float2(S0, S1);
}

// ---- k_scanB: self prefix over Asum/Ssum + y_hat emit from G1/G2 ----
__global__ __launch_bounds__(256) void k_scanB(
    const unsigned int* __restrict__ G1, const float* __restrict__ G2,
    const float* __restrict__ Asum, const float* __restrict__ Ssum,
    const float* __restrict__ z0, unsigned short* __restrict__ yh)
{
  const int tid = threadIdx.x;
  const int n0 = tid*4;
  const int ch = blockIdx.x, b = blockIdx.y;
  float z[4];
  #pragma unroll
  for (int j = 0; j < 4; j++) z[j] = z0[b*N_ + n0 + j];
  for (int c2 = 0; c2 < ch; c2++){
    const size_t idx = (size_t)(b*NCH + c2)*N_ + n0;
    float4 Av = *(const float4*)(Asum + idx);
    float4 Sv = *(const float4*)(Ssum + idx);
    z[0] = fmaf(Av.x, z[0], Sv.x);
    z[1] = fmaf(Av.y, z[1], Sv.y);
    z[2] = fmaf(Av.z, z[2], Sv.z);
    z[3] = fmaf(Av.w, z[3], Sv.w);
  }
  const size_t base = (size_t)(b*T_ + ch*TC)*N_ + n0;
  const unsigned int* g1 = G1 + base;
  const float* g2 = G2 + base;
  unsigned short* Y = yh + base;
  #pragma unroll 4
  for (int i = 0; i < TC; i++){
    uint4 pac = *(const uint4*)g1;
    float4 bu = *(const float4*)g2;
    us4 ow;
    #pragma unroll
    for (int j = 0; j < 4; j++){
      unsigned int p = j==0 ? pac.x : j==1 ? pac.y : j==2 ? pac.z : pac.w;
      float buj     = j==0 ? bu.x  : j==1 ? bu.y  : j==2 ? bu.z  : bu.w;
      float a = bf2f((unsigned short)(p & 0xffffu));
      float c = bf2f((unsigned short)(p >> 16));
      float yv = c * z[j];
      z[j] = fmaf(a, z[j], buj);
      ow[j] = f2bf(yv);
    }
    *(us4*)Y = ow;
    g1 += N_; g2 += N_; Y += N_;
  }
}

extern "C" void kernel_launch(void* const* d_in, const int* in_sizes, int n_in,
                              void* d_out, int out_size, void* d_ws, size_t ws_size,
                              hipStream_t stream)
{
  const float* u    = (const float*)d_in[0];
  const float* z0   = (const float*)d_in[1];
  const float* Win  = (const float*)d_in[2];
  const float* Wout = (const float*)d_in[3];
  const float* pnw  = (const float*)d_in[4];
  const float* pnb  = (const float*)d_in[5];
  const float* alog = (const float*)d_in[6];
  const float* dbias= (const float*)d_in[7];
  const float* lgam = (const float*)d_in[8];

  char* ws = (char*)d_ws;
  size_t off = 0;
  auto alloc = [&](size_t bytes) -> void* {
    void* p = ws + off;
    off += (bytes + 255) & ~(size_t)255;
    return p;
  };
  float*          sc     = (float*)         alloc(1024);
  unsigned short* u16    = (unsigned short*)alloc((size_t)8192*1024*2);
  unsigned short* Wcat16 = (unsigned short*)alloc((size_t)4096*1024*2);
  unsigned short* Wout16 = (unsigned short*)alloc((size_t)1024*1024*2);
  unsigned int*   G1     = (unsigned int*)  alloc((size_t)8192*1024*4);
  float*          G2     = (float*)         alloc((size_t)8192*1024*4);
  unsigned short* yh16   = (unsigned short*)alloc((size_t)8192*1024*2);
  unsigned short* Hping  = (unsigned short*)alloc((size_t)2*1024*1024*2);
  unsigned short* Hpong  = (unsigned short*)alloc((size_t)2*1024*1024*2);
  float*          Asum   = (float*)alloc((size_t)B_*NCH*N_*4);
  float*          Ssum   = (float*)alloc((size_t)B_*NCH*N_*4);

  k_convert_all<<<CONV_BLOCKS, 256, 0, stream>>>(u, Win, pnw, Wout, u16, Wcat16, Wout16, sc);

  // spectral-norm chains
  dim3 gsq(136, 1, 2);
  k_sq<<<gsq, 256, 0, stream>>>(Wcat16, Hping, Wout16, Hping + (size_t)1024*1024, sc, 0);
  unsigned short* hin = Hping;
  unsigned short* hout = Hpong;
  for (int s = 1; s <= SQN; s++){
    k_sq<<<gsq, 256, 0, stream>>>(hin, hout, hin + (size_t)1024*1024, hout + (size_t)1024*1024, sc, s);
    unsigned short* t = hin; hin = hout; hout = t;
  }

  // gated P-GEMM: swapped-operand epilogue + LDS-staged coalesced G1/G2 stores
  dim3 g1(4096/128, 8192/128);
  k_pgemm<<<g1, 256, 0, stream>>>(u16, Wcat16, alog, dbias, pnb, lgam, sc, G1, G2);

  // chunk (A,S) then prefix+emit
  dim3 ga(NCH, 2, B_);
  k_scanA<<<ga, 256, 0, stream>>>(G1, G2, Asum, Ssum);
  dim3 gb(NCH, B_);
  k_scanB<<<gb, 256, 0, stream>>>(G1, G2, Asum, Ssum, z0, yh16);

  // y = (y_hat @ W_out^T) * inv_scale(sc,1)  (fp32 out)
  dim3 g2(1024/128, 8192/128);
  k_gemm<0><<<g2, 256, 0, stream>>>(yh16, Wout16, d_out, 8192, 1024, 1024, sc, 1);
}

// Round 17
// 264.374 us; speedup vs baseline: 1.4917x; 1.0499x over previous
//
#include <hip/hip_runtime.h>
#include <stdint.h>

#define B_ 4
#define T_ 2048
#define D_ 1024
#define N_ 1024
#define TC 16
#define NCH (T_/TC)
#define SQN 6   // squaring GEMMs after gram; +1 effective doubling via fused Frobenius

typedef __attribute__((ext_vector_type(4))) float f32x4;
typedef __attribute__((ext_vector_type(8))) short bf16x8;
typedef __attribute__((ext_vector_type(4))) unsigned short us4;

__device__ __forceinline__ unsigned short f2bf(float f){
  unsigned int u = __float_as_uint(f);
  return (unsigned short)((u + 0x7fffu + ((u >> 16) & 1u)) >> 16);
}
__device__ __forceinline__ float bf2f(unsigned short h){
  return __uint_as_float(((unsigned int)h) << 16);
}

// inverse spectral scale from trace chain (z=0: W_in, z=1: W_out)
__device__ __forceinline__ float inv_scale(const float* __restrict__ sc, int z){
  float ll = 0.f, w = 1.f, t = 1.f;
  #pragma unroll
  for (int i = 0; i <= SQN; i++){
    t = sc[8 + 2*i + z];
    ll += w * __logf(t);
    w *= 0.5f;
  }
  float F = sc[8 + 2*(SQN+1) + z];
  ll += w * __logf(F / (t*t));
  float sig = fmaxf(__expf(0.5f * ll), 1e-5f);
  return 1.f / fmaxf(sig, 1.f);
}

__device__ __forceinline__ float softplusf(float x){
  return (x > 0.f) ? (x + __logf(1.f + __expf(-x))) : __logf(1.f + __expf(x));
}
__device__ __forceinline__ float tanhfastf(float x){
  float e = __expf(2.f * x);
  return 1.f - 2.f/(e + 1.f);
}
__device__ __forceinline__ float tanhrcpf(float x){
  float e = __expf(2.f * x);
  return 1.f - 2.f*__builtin_amdgcn_rcpf(e + 1.f);
}

// ---- fused fp32->bf16 conversion + INTERLEAVE of weight rows + sc zero-init ----
// Wcat16 row (4n+s): s=0 -> W_in[n], s=1..3 -> pn_w[(s-1)*N + n] (delta, b, c).
#define U4    2097152
#define WIN4   262144
#define PNW4   786432
#define WOUT4  262144
#define CONV_BLOCKS ((U4 + WIN4 + PNW4 + WOUT4 + 255)/256)

__global__ void k_convert_all(const float* __restrict__ u, const float* __restrict__ Win,
                              const float* __restrict__ pnw, const float* __restrict__ Wout,
                              unsigned short* __restrict__ u16, unsigned short* __restrict__ Wcat16,
                              unsigned short* __restrict__ Wout16, float* __restrict__ sc){
  if (blockIdx.x == 0 && threadIdx.x < 64) sc[threadIdx.x] = 0.f;
  long i = (long)blockIdx.x * 256 + threadIdx.x;
  const float* src; long o; size_t didx; unsigned short* dbuf;
  if (i < U4){
    src = u; o = i; dbuf = u16; didx = (size_t)o;
  } else if (i < U4+WIN4){
    o = i - U4; src = Win;
    int n = (int)(o >> 8), c4 = (int)(o & 255);
    dbuf = Wcat16; didx = (size_t)(4*n)*256 + c4;
  } else if (i < U4+WIN4+PNW4){
    o = i - (U4+WIN4); src = pnw;
    int m = (int)(o >> 8), c4 = (int)(o & 255);
    int s = (m >> 10) + 1, n = m & 1023;
    dbuf = Wcat16; didx = (size_t)(4*n + s)*256 + c4;
  } else if (i < U4+WIN4+PNW4+WOUT4){
    o = i - (U4+WIN4+PNW4); src = Wout; dbuf = Wout16; didx = (size_t)o;
  } else return;
  float4 v = ((const float4*)src)[o];
  us4 w;
  w.x = f2bf(v.x); w.y = f2bf(v.y); w.z = f2bf(v.z); w.w = f2bf(v.w);
  ((us4*)dbuf)[didx] = w;
}

__device__ __forceinline__ void load_lds16(const unsigned short* g, unsigned short* l){
  __builtin_amdgcn_global_load_lds((const __attribute__((address_space(1))) void*)g,
                                   (__attribute__((address_space(3))) void*)l, 16, 0, 0);
}

// ==== gated P-GEMM: swapped MFMA operands; per-lane gate math on accumulator;
// LDS-staged coalesced G1/G2 stores; chunk (A,S) reduction fused (reads the LDS
// slab, writes Asum/Ssum directly — k_scanA eliminated).
__global__ __launch_bounds__(256) void k_pgemm(
    const unsigned short* __restrict__ A,      // u16 [8192][1024]
    const unsigned short* __restrict__ Bmat,   // Wcat16 [4096][1024] interleaved
    const float* __restrict__ alog, const float* __restrict__ dbias,
    const float* __restrict__ pnb, const float* __restrict__ lgam,
    const float* __restrict__ sc,
    unsigned int* __restrict__ G1,
    float* __restrict__ G2,
    float* __restrict__ Asum, float* __restrict__ Ssum)
{
  __shared__ alignas(16) char smem[36864];   // GEMM: As(16K)+Bs(16K); epilogue: g1s/g2s
  unsigned short* As = (unsigned short*)smem;
  unsigned short* Bs = (unsigned short*)(smem + 16384);
  const int tid = threadIdx.x;
  const int wid = tid >> 6;
  const int lane = tid & 63;
  const int bn = blockIdx.x, bm = blockIdx.y;
  const int K = 1024;

  const int wr = wid >> 1, wc = wid & 1;
  const int rg = lane >> 3;
  const int cby = (lane & 7) << 4;
  const int srow0 = wid * 32;
  const int frow = lane & 15;
  const int kgrp = lane >> 4;

  const unsigned short* ap[4];
  const unsigned short* bp[4];
  unsigned short* adst[4];
  unsigned short* bdst[4];
  #pragma unroll
  for (int i = 0; i < 4; i++){
    int r = srow0 + i*8 + rg;
    int cb = cby ^ ((r & 7) << 4);
    ap[i] = A    + (size_t)(bm*128 + r)*K + (cb >> 1);
    bp[i] = Bmat + (size_t)(bn*128 + r)*K + (cb >> 1);
    adst[i] = As + (srow0 + i*8)*64;
    bdst[i] = Bs + (srow0 + i*8)*64;
  }
  int aoff[4][2], boff[4][2];
  #pragma unroll
  for (int m = 0; m < 4; m++){
    int r = wr*64 + m*16 + frow;
    #pragma unroll
    for (int kk = 0; kk < 2; kk++)
      aoff[m][kk] = r*128 + ((kk*64 + kgrp*16) ^ ((r & 7) << 4));
  }
  #pragma unroll
  for (int n2 = 0; n2 < 4; n2++){
    int r = wc*64 + n2*16 + frow;
    #pragma unroll
    for (int kk = 0; kk < 2; kk++)
      boff[n2][kk] = r*128 + ((kk*64 + kgrp*16) ^ ((r & 7) << 4));
  }

  f32x4 acc[4][4] = {};

  for (int kt = 0; kt < K; kt += 64){
    #pragma unroll
    for (int i = 0; i < 4; i++){
      load_lds16(ap[i], adst[i]);
      load_lds16(bp[i], bdst[i]);
      ap[i] += 64; bp[i] += 64;
    }
    __syncthreads();
    #pragma unroll
    for (int kk = 0; kk < 2; kk++){
      bf16x8 af[4], bfv[4];
      #pragma unroll
      for (int m = 0; m < 4; m++)
        af[m] = *(const bf16x8*)((const char*)As + aoff[m][kk]);
      #pragma unroll
      for (int n2 = 0; n2 < 4; n2++)
        bfv[n2] = *(const bf16x8*)((const char*)Bs + boff[n2][kk]);
      // swapped operands: D-row <-> W-row (streams), D-col <-> u-row (t)
      #pragma unroll
      for (int m = 0; m < 4; m++)
        #pragma unroll
        for (int n2 = 0; n2 < 4; n2++)
          acc[m][n2] = __builtin_amdgcn_mfma_f32_16x16x32_bf16(bfv[n2], af[m], acc[m][n2], 0, 0, 0);
    }
    __syncthreads();
  }

  // ===== per-lane gated epilogue; LDS staging =====
  unsigned int* g1s = (unsigned int*)smem;            // [128][36] u32
  float*        g2s = (float*)(smem + 18432);         // [128][36] f32

  const float ginv = __expf(lgam[0]) * inv_scale(sc, 0);
  float alpha[4], bd[4], bb[4], bc[4];
  #pragma unroll
  for (int nw = 0; nw < 4; nw++){
    int n = bn*32 + wc*16 + nw*4 + kgrp;
    alpha[nw] = softplusf(alog[n]);
    bd[nw] = dbias[n] + pnb[n];
    bb[nw] = pnb[N_ + n];
    bc[nw] = pnb[2*N_ + n];
  }
  #pragma unroll
  for (int mu = 0; mu < 4; mu++){
    const int tl = wr*64 + mu*16 + frow;
    #pragma unroll
    for (int nw = 0; nw < 4; nw++){
      const int nl = wc*16 + nw*4 + kgrp;
      f32x4 v = acc[mu][nw];
      float lp = __logf(1.f + __expf(v[1] + bd[nw]));
      float av = fminf(__expf(-alpha[nw]*lp), 1.f - 1e-4f);
      float bv = tanhrcpf(v[2] + bb[nw]);
      float cv = tanhrcpf(v[3] + bc[nw]);
      float p = av*av + cv*cv;
      float r = bv*bv;
      float q = av*bv;
      float pr = p - r;
      float disc = pr*pr + 4.f*q*q;
      float lam = 0.5f*(p + r + sqrtf(disc + 1e-12f));
      float inv = fminf(rsqrtf(lam + 1e-12f), 1.f);
      float a = av * inv;
      float c = cv * inv;
      float bu = (bv * inv) * (v[0] * ginv);
      g1s[tl*36 + nl] = (unsigned int)f2bf(a) | ((unsigned int)f2bf(c) << 16);
      g2s[tl*36 + nl] = bu;
    }
  }
  __syncthreads();
  // coalesced flush: 4 rounds x 256 threads cover 128 rows x 8 segs of 16B
  const size_t t0b = (size_t)bm * 128;
  const int nb = bn*32;
  #pragma unroll
  for (int r = 0; r < 4; r++){
    int flat = r*256 + tid;
    int tl = flat >> 3, seg = flat & 7;
    uint4  v1 = *(const uint4*)(g1s + tl*36 + seg*4);
    float4 v2 = *(const float4*)(g2s + tl*36 + seg*4);
    *(uint4*)(G1 + (t0b + tl)*N_ + nb + seg*4) = v1;
    *(float4*)(G2 + (t0b + tl)*N_ + nb + seg*4) = v2;
  }
  // fused chunk (A,S): 256 threads = 8 chunks x 32 n; serial 16-step chain from LDS
  {
    const int chl = tid >> 5;          // 0..7
    const int nl  = tid & 31;          // 0..31
    float Ar = 1.f, Sr = 0.f;
    #pragma unroll
    for (int i = 0; i < 16; i++){
      int row = chl*16 + i;
      float a = bf2f((unsigned short)(g1s[row*36 + nl] & 0xffffu));
      float bu = g2s[row*36 + nl];
      Sr = fmaf(a, Sr, bu);
      Ar *= a;
    }
    const size_t gch = (size_t)bm*8 + chl;        // global chunk = (b*NCH + ch)
    Asum[gch*N_ + nb + nl] = Ar;
    Ssum[gch*N_ + nb + nl] = Sr;
  }
}

// ---- out-GEMM: C[M,N] = (A[M,K] * B[N,K]^T) * inv_scale(step)  (128^2, m97) ----
template<int OUTBF16>
__global__ __launch_bounds__(256) void k_gemm(
    const unsigned short* __restrict__ A,
    const unsigned short* __restrict__ Bmat,
    void* __restrict__ C0,
    int M, int N, int K,
    const float* __restrict__ sc, int step)
{
  __shared__ alignas(16) unsigned short As[128*64];
  __shared__ alignas(16) unsigned short Bs[128*64];
  const int tid = threadIdx.x;
  const int wid = tid >> 6;
  const int lane = tid & 63;
  const int bn = blockIdx.x, bm = blockIdx.y;

  char* C = (char*)C0;
  float outscale = (step >= 0) ? inv_scale(sc, step) : 1.f;

  const int wr = wid >> 1, wc = wid & 1;
  const int rg = lane >> 3;
  const int cby = (lane & 7) << 4;
  const int srow0 = wid * 32;
  const int frow = lane & 15;
  const int kgrp = lane >> 4;

  const unsigned short* ap[4];
  const unsigned short* bp[4];
  unsigned short* adst[4];
  unsigned short* bdst[4];
  #pragma unroll
  for (int i = 0; i < 4; i++){
    int r = srow0 + i*8 + rg;
    int cb = cby ^ ((r & 7) << 4);
    ap[i] = A    + (size_t)(bm*128 + r)*K + (cb >> 1);
    bp[i] = Bmat + (size_t)(bn*128 + r)*K + (cb >> 1);
    adst[i] = As + (srow0 + i*8)*64;
    bdst[i] = Bs + (srow0 + i*8)*64;
  }
  int aoff[4][2], boff[4][2];
  #pragma unroll
  for (int m = 0; m < 4; m++){
    int r = wr*64 + m*16 + frow;
    #pragma unroll
    for (int kk = 0; kk < 2; kk++)
      aoff[m][kk] = r*128 + ((kk*64 + kgrp*16) ^ ((r & 7) << 4));
  }
  #pragma unroll
  for (int n2 = 0; n2 < 4; n2++){
    int r = wc*64 + n2*16 + frow;
    #pragma unroll
    for (int kk = 0; kk < 2; kk++)
      boff[n2][kk] = r*128 + ((kk*64 + kgrp*16) ^ ((r & 7) << 4));
  }

  f32x4 acc[4][4] = {};

  for (int kt = 0; kt < K; kt += 64){
    #pragma unroll
    for (int i = 0; i < 4; i++){
      load_lds16(ap[i], adst[i]);
      load_lds16(bp[i], bdst[i]);
      ap[i] += 64; bp[i] += 64;
    }
    __syncthreads();
    #pragma unroll
    for (int kk = 0; kk < 2; kk++){
      bf16x8 af[4], bfv[4];
      #pragma unroll
      for (int m = 0; m < 4; m++)
        af[m] = *(const bf16x8*)((const char*)As + aoff[m][kk]);
      #pragma unroll
      for (int n2 = 0; n2 < 4; n2++)
        bfv[n2] = *(const bf16x8*)((const char*)Bs + boff[n2][kk]);
      #pragma unroll
      for (int m = 0; m < 4; m++)
        #pragma unroll
        for (int n2 = 0; n2 < 4; n2++)
          acc[m][n2] = __builtin_amdgcn_mfma_f32_16x16x32_bf16(af[m], bfv[n2], acc[m][n2], 0, 0, 0);
    }
    __syncthreads();
  }

  const int row0 = bm*128 + wr*64;
  const int col0 = bn*128 + wc*64 + frow;
  #pragma unroll
  for (int m = 0; m < 4; m++){
    #pragma unroll
    for (int n2 = 0; n2 < 4; n2++){
      const int col = col0 + n2*16;
      const int rb = row0 + m*16 + kgrp*4;
      #pragma unroll
      for (int j = 0; j < 4; j++){
        float v = acc[m][n2][j] * outscale;
        if (OUTBF16) ((unsigned short*)C)[(size_t)(rb + j)*N + col] = f2bf(v);
        else         ((float*)C)[(size_t)(rb + j)*N + col] = v;
      }
    }
  }
}

// ---- triangular squaring-chain GEMM (C = X*X^T symmetric, upper tiles only) ----
__global__ __launch_bounds__(256) void k_sq(
    const unsigned short* __restrict__ A0, unsigned short* __restrict__ C0,
    const unsigned short* __restrict__ A1, unsigned short* __restrict__ C1,
    float* __restrict__ sc, int step)
{
  __shared__ alignas(16) unsigned short As0[64*128], Bs0[64*128];
  __shared__ alignas(16) unsigned short As1[64*128], Bs1[64*128];
  const int tid = threadIdx.x;
  const int wid = tid >> 6;
  const int lane = tid & 63;
  const int z = blockIdx.z;

  int x = blockIdx.x, bm = 0;
  while (x >= 16 - bm){ x -= 16 - bm; bm++; }
  const int bn = bm + x;

  const unsigned short* A = z ? A1 : A0;
  unsigned short* C = z ? C1 : C0;
  const size_t rs = (step == 0 && z == 0) ? 4096 : 1024;
  float outscale = 1.f;
  if (step > 0){ float t = sc[8 + (step-1)*2 + z]; outscale = 1.f/(t*t); }

  const int wr = wid >> 1, wc = wid & 1;
  const int frow = lane & 15;
  const int kgrp = lane >> 4;

  const int srl = lane >> 4;
  const int sgr = lane & 15;
  const int swzr = wid*4 + srl;
  const int scol_e = ((sgr ^ swzr) << 3);

  const size_t Arow = (size_t)bm * 64;
  const size_t Brow = (size_t)bn * 64;

  f32x4 acc[2][2] = {};

  auto stage = [&](unsigned short* as, unsigned short* bs, int t){
    const int kt = t * 128;
    #pragma unroll
    for (int i = 0; i < 4; i++){
      int r = i*16 + wid*4 + srl;
      load_lds16(A + (Arow + r)*rs + kt + scol_e, as + (i*16 + wid*4)*128);
      load_lds16(A + (Brow + r)*rs + kt + scol_e, bs + (i*16 + wid*4)*128);
    }
  };

  auto compute = [&](const unsigned short* as, const unsigned short* bs){
    #pragma unroll
    for (int ks = 0; ks < 4; ks++){
      const int kb = ks*64 + kgrp*16;
      bf16x8 af[2], bfv[2];
      #pragma unroll
      for (int m = 0; m < 2; m++){
        int r = wr*32 + m*16 + frow;
        af[m] = *(const bf16x8*)((const char*)as + r*256 + (kb ^ (frow << 4)));
      }
      #pragma unroll
      for (int n2 = 0; n2 < 2; n2++){
        int r = wc*32 + n2*16 + frow;
        bfv[n2] = *(const bf16x8*)((const char*)bs + r*256 + (kb ^ (frow << 4)));
      }
      #pragma unroll
      for (int m = 0; m < 2; m++)
        #pragma unroll
        for (int n2 = 0; n2 < 2; n2++)
          acc[m][n2] = __builtin_amdgcn_mfma_f32_16x16x32_bf16(af[m], bfv[n2], acc[m][n2], 0, 0, 0);
    }
  };

  stage(As0, Bs0, 0);
  __syncthreads();
  for (int t2 = 0; t2 < 8; t2 += 2){
    if (t2 + 1 < 8) stage(As1, Bs1, t2 + 1);
    compute(As0, Bs0);
    __syncthreads();
    if (t2 + 2 < 8) stage(As0, Bs0, t2 + 2);
    compute(As1, Bs1);
    __syncthreads();
  }

  const int row0 = bm*64 + wr*32;
  const int col0 = bn*64 + wc*32 + frow;
  float fr = 0.f;
  #pragma unroll
  for (int m = 0; m < 2; m++){
    #pragma unroll
    for (int n2 = 0; n2 < 2; n2++){
      const int col = col0 + n2*16;
      const int rb = row0 + m*16 + kgrp*4;
      us4 tw;
      #pragma unroll
      for (int j = 0; j < 4; j++){
        float v = acc[m][n2][j] * outscale;
        unsigned short h = f2bf(v);
        C[(size_t)(rb + j)*1024 + col] = h;
        tw[j] = h;
        fr += v*v;
      }
      if (bm != bn)
        *(us4*)(C + (size_t)col*1024 + rb) = tw;
    }
  }
  if (bm == bn && wr == wc){
    int j = frow - kgrp*4;
    if (j >= 0 && j < 4){
      float d = (acc[0][0][j] + acc[1][1][j]) * outscale;
      atomicAdd(&sc[8 + step*2 + z], d);
    }
  }
  if (step == SQN){
    if (bm != bn) fr *= 2.f;
    #pragma unroll
    for (int off = 32; off; off >>= 1) fr += __shfl_down(fr, off, 64);
    if (lane == 0) atomicAdd(&sc[8 + 2*(SQN+1) + z], fr);
  }
}

// ---- k_scanB: self prefix over Asum/Ssum + y_hat emit from G1/G2 ----
__global__ __launch_bounds__(256) void k_scanB(
    const unsigned int* __restrict__ G1, const float* __restrict__ G2,
    const float* __restrict__ Asum, const float* __restrict__ Ssum,
    const float* __restrict__ z0, unsigned short* __restrict__ yh)
{
  const int tid = threadIdx.x;
  const int n0 = tid*4;
  const int ch = blockIdx.x, b = blockIdx.y;
  float z[4];
  #pragma unroll
  for (int j = 0; j < 4; j++) z[j] = z0[b*N_ + n0 + j];
  for (int c2 = 0; c2 < ch; c2++){
    const size_t idx = (size_t)(b*NCH + c2)*N_ + n0;
    float4 Av = *(const float4*)(Asum + idx);
    float4 Sv = *(const float4*)(Ssum + idx);
    z[0] = fmaf(Av.x, z[0], Sv.x);
    z[1] = fmaf(Av.y, z[1], Sv.y);
    z[2] = fmaf(Av.z, z[2], Sv.z);
    z[3] = fmaf(Av.w, z[3], Sv.w);
  }
  const size_t base = (size_t)(b*T_ + ch*TC)*N_ + n0;
  const unsigned int* g1 = G1 + base;
  const float* g2 = G2 + base;
  unsigned short* Y = yh + base;
  #pragma unroll 4
  for (int i = 0; i < TC; i++){
    uint4 pac = *(const uint4*)g1;
    float4 bu = *(const float4*)g2;
    us4 ow;
    #pragma unroll
    for (int j = 0; j < 4; j++){
      unsigned int p = j==0 ? pac.x : j==1 ? pac.y : j==2 ? pac.z : pac.w;
      float buj     = j==0 ? bu.x  : j==1 ? bu.y  : j==2 ? bu.z  : bu.w;
      float a = bf2f((unsigned short)(p & 0xffffu));
      float c = bf2f((unsigned short)(p >> 16));
      float yv = c * z[j];
      z[j] = fmaf(a, z[j], buj);
      ow[j] = f2bf(yv);
    }
    *(us4*)Y = ow;
    g1 += N_; g2 += N_; Y += N_;
  }
}

extern "C" void kernel_launch(void* const* d_in, const int* in_sizes, int n_in,
                              void* d_out, int out_size, void* d_ws, size_t ws_size,
                              hipStream_t stream)
{
  const float* u    = (const float*)d_in[0];
  const float* z0   = (const float*)d_in[1];
  const float* Win  = (const float*)d_in[2];
  const float* Wout = (const float*)d_in[3];
  const float* pnw  = (const float*)d_in[4];
  const float* pnb  = (const float*)d_in[5];
  const float* alog = (const float*)d_in[6];
  const float* dbias= (const float*)d_in[7];
  const float* lgam = (const float*)d_in[8];

  char* ws = (char*)d_ws;
  size_t off = 0;
  auto alloc = [&](size_t bytes) -> void* {
    void* p = ws + off;
    off += (bytes + 255) & ~(size_t)255;
    return p;
  };
  float*          sc     = (float*)         alloc(1024);
  unsigned short* u16    = (unsigned short*)alloc((size_t)8192*1024*2);
  unsigned short* Wcat16 = (unsigned short*)alloc((size_t)4096*1024*2);
  unsigned short* Wout16 = (unsigned short*)alloc((size_t)1024*1024*2);
  unsigned int*   G1     = (unsigned int*)  alloc((size_t)8192*1024*4);
  float*          G2     = (float*)         alloc((size_t)8192*1024*4);
  unsigned short* yh16   = (unsigned short*)alloc((size_t)8192*1024*2);
  unsigned short* Hping  = (unsigned short*)alloc((size_t)2*1024*1024*2);
  unsigned short* Hpong  = (unsigned short*)alloc((size_t)2*1024*1024*2);
  float*          Asum   = (float*)alloc((size_t)B_*NCH*N_*4);
  float*          Ssum   = (float*)alloc((size_t)B_*NCH*N_*4);

  k_convert_all<<<CONV_BLOCKS, 256, 0, stream>>>(u, Win, pnw, Wout, u16, Wcat16, Wout16, sc);

  // spectral-norm chains
  dim3 gsq(136, 1, 2);
  k_sq<<<gsq, 256, 0, stream>>>(Wcat16, Hping, Wout16, Hping + (size_t)1024*1024, sc, 0);
  unsigned short* hin = Hping;
  unsigned short* hout = Hpong;
  for (int s = 1; s <= SQN; s++){
    k_sq<<<gsq, 256, 0, stream>>>(hin, hout, hin + (size_t)1024*1024, hout + (size_t)1024*1024, sc, s);
    unsigned short* t = hin; hin = hout; hout = t;
  }

  // gated P-GEMM: epilogue emits G1/G2 + chunk (A,S) (scanA fused)
  dim3 g1(4096/128, 8192/128);
  k_pgemm<<<g1, 256, 0, stream>>>(u16, Wcat16, alog, dbias, pnb, lgam, sc, G1, G2, Asum, Ssum);

  // prefix + y_hat emit
  dim3 gb(NCH, B_);
  k_scanB<<<gb, 256, 0, stream>>>(G1, G2, Asum, Ssum, z0, yh16);

  // y = (y_hat @ W_out^T) * inv_scale(sc,1)  (fp32 out)
  dim3 g2(1024/128, 8192/128);
  k_gemm<0><<<g2, 256, 0, stream>>>(yh16, Wout16, d_out, 8192, 1024, 1024, sc, 1);
}

// Round 18
// 263.171 us; speedup vs baseline: 1.4985x; 1.0046x over previous
//
#include <hip/hip_runtime.h>
#include <stdint.h>

#define B_ 4
#define T_ 2048
#define D_ 1024
#define N_ 1024
#define TC 16
#define NCH (T_/TC)
#define SQN 6   // squaring GEMMs after gram; +1 effective doubling via fused Frobenius

typedef __attribute__((ext_vector_type(4))) float f32x4;
typedef __attribute__((ext_vector_type(8))) short bf16x8;
typedef __attribute__((ext_vector_type(4))) unsigned short us4;

__device__ __forceinline__ unsigned short f2bf(float f){
  unsigned int u = __float_as_uint(f);
  return (unsigned short)((u + 0x7fffu + ((u >> 16) & 1u)) >> 16);
}
__device__ __forceinline__ float bf2f(unsigned short h){
  return __uint_as_float(((unsigned int)h) << 16);
}

// inverse spectral scale from trace chain (z=0: W_in, z=1: W_out)
__device__ __forceinline__ float inv_scale(const float* __restrict__ sc, int z){
  float ll = 0.f, w = 1.f, t = 1.f;
  #pragma unroll
  for (int i = 0; i <= SQN; i++){
    t = sc[8 + 2*i + z];
    ll += w * __logf(t);
    w *= 0.5f;
  }
  float F = sc[8 + 2*(SQN+1) + z];
  ll += w * __logf(F / (t*t));
  float sig = fmaxf(__expf(0.5f * ll), 1e-5f);
  return 1.f / fmaxf(sig, 1.f);
}

__device__ __forceinline__ float softplusf(float x){
  return (x > 0.f) ? (x + __logf(1.f + __expf(-x))) : __logf(1.f + __expf(x));
}
__device__ __forceinline__ float tanhrcpf(float x){
  float e = __expf(2.f * x);
  return 1.f - 2.f*__builtin_amdgcn_rcpf(e + 1.f);
}

// ---- fused fp32->bf16 conversion + INTERLEAVE of weight rows + sc zero-init ----
// Wcat16 row (4n+s): s=0 -> W_in[n], s=1..3 -> pn_w[(s-1)*N + n] (delta, b, c).
#define U4    2097152
#define WIN4   262144
#define PNW4   786432
#define WOUT4  262144
#define CONV_BLOCKS ((U4 + WIN4 + PNW4 + WOUT4 + 255)/256)

__global__ void k_convert_all(const float* __restrict__ u, const float* __restrict__ Win,
                              const float* __restrict__ pnw, const float* __restrict__ Wout,
                              unsigned short* __restrict__ u16, unsigned short* __restrict__ Wcat16,
                              unsigned short* __restrict__ Wout16, float* __restrict__ sc){
  if (blockIdx.x == 0 && threadIdx.x < 64) sc[threadIdx.x] = 0.f;
  long i = (long)blockIdx.x * 256 + threadIdx.x;
  const float* src; long o; size_t didx; unsigned short* dbuf;
  if (i < U4){
    src = u; o = i; dbuf = u16; didx = (size_t)o;
  } else if (i < U4+WIN4){
    o = i - U4; src = Win;
    int n = (int)(o >> 8), c4 = (int)(o & 255);
    dbuf = Wcat16; didx = (size_t)(4*n)*256 + c4;
  } else if (i < U4+WIN4+PNW4){
    o = i - (U4+WIN4); src = pnw;
    int m = (int)(o >> 8), c4 = (int)(o & 255);
    int s = (m >> 10) + 1, n = m & 1023;
    dbuf = Wcat16; didx = (size_t)(4*n + s)*256 + c4;
  } else if (i < U4+WIN4+PNW4+WOUT4){
    o = i - (U4+WIN4+PNW4); src = Wout; dbuf = Wout16; didx = (size_t)o;
  } else return;
  float4 v = ((const float4*)src)[o];
  us4 w;
  w.x = f2bf(v.x); w.y = f2bf(v.y); w.z = f2bf(v.z); w.w = f2bf(v.w);
  ((us4*)dbuf)[didx] = w;
}

__device__ __forceinline__ void load_lds16(const unsigned short* g, unsigned short* l){
  __builtin_amdgcn_global_load_lds((const __attribute__((address_space(1))) void*)g,
                                   (__attribute__((address_space(3))) void*)l, 16, 0, 0);
}

// ==== gated P-GEMM: swapped MFMA operands; per-lane gate math on accumulator;
// fused chunk-scan converts (a,c,bu) -> (u1,u2) = (c*Aloc, c*Sloc) packed bf16
// so the emit kernel is a pure fma stream: yh_t = u1*z_c + u2. Also emits
// per-chunk (Asum,Ssum) for the global prefix.
__global__ __launch_bounds__(256) void k_pgemm(
    const unsigned short* __restrict__ A,      // u16 [8192][1024]
    const unsigned short* __restrict__ Bmat,   // Wcat16 [4096][1024] interleaved
    const float* __restrict__ alog, const float* __restrict__ dbias,
    const float* __restrict__ pnb, const float* __restrict__ lgam,
    const float* __restrict__ sc,
    unsigned int* __restrict__ U,              // [t][n] packed (u1, u2) bf16
    float* __restrict__ Asum, float* __restrict__ Ssum)
{
  __shared__ alignas(16) char smem[36864];   // GEMM: As(16K)+Bs(16K); epilogue: g1s/g2s
  unsigned short* As = (unsigned short*)smem;
  unsigned short* Bs = (unsigned short*)(smem + 16384);
  const int tid = threadIdx.x;
  const int wid = tid >> 6;
  const int lane = tid & 63;
  const int bn = blockIdx.x, bm = blockIdx.y;
  const int K = 1024;

  const int wr = wid >> 1, wc = wid & 1;
  const int rg = lane >> 3;
  const int cby = (lane & 7) << 4;
  const int srow0 = wid * 32;
  const int frow = lane & 15;
  const int kgrp = lane >> 4;

  const unsigned short* ap[4];
  const unsigned short* bp[4];
  unsigned short* adst[4];
  unsigned short* bdst[4];
  #pragma unroll
  for (int i = 0; i < 4; i++){
    int r = srow0 + i*8 + rg;
    int cb = cby ^ ((r & 7) << 4);
    ap[i] = A    + (size_t)(bm*128 + r)*K + (cb >> 1);
    bp[i] = Bmat + (size_t)(bn*128 + r)*K + (cb >> 1);
    adst[i] = As + (srow0 + i*8)*64;
    bdst[i] = Bs + (srow0 + i*8)*64;
  }
  int aoff[4][2], boff[4][2];
  #pragma unroll
  for (int m = 0; m < 4; m++){
    int r = wr*64 + m*16 + frow;
    #pragma unroll
    for (int kk = 0; kk < 2; kk++)
      aoff[m][kk] = r*128 + ((kk*64 + kgrp*16) ^ ((r & 7) << 4));
  }
  #pragma unroll
  for (int n2 = 0; n2 < 4; n2++){
    int r = wc*64 + n2*16 + frow;
    #pragma unroll
    for (int kk = 0; kk < 2; kk++)
      boff[n2][kk] = r*128 + ((kk*64 + kgrp*16) ^ ((r & 7) << 4));
  }

  f32x4 acc[4][4] = {};

  for (int kt = 0; kt < K; kt += 64){
    #pragma unroll
    for (int i = 0; i < 4; i++){
      load_lds16(ap[i], adst[i]);
      load_lds16(bp[i], bdst[i]);
      ap[i] += 64; bp[i] += 64;
    }
    __syncthreads();
    #pragma unroll
    for (int kk = 0; kk < 2; kk++){
      bf16x8 af[4], bfv[4];
      #pragma unroll
      for (int m = 0; m < 4; m++)
        af[m] = *(const bf16x8*)((const char*)As + aoff[m][kk]);
      #pragma unroll
      for (int n2 = 0; n2 < 4; n2++)
        bfv[n2] = *(const bf16x8*)((const char*)Bs + boff[n2][kk]);
      // swapped operands: D-row <-> W-row (streams), D-col <-> u-row (t)
      #pragma unroll
      for (int m = 0; m < 4; m++)
        #pragma unroll
        for (int n2 = 0; n2 < 4; n2++)
          acc[m][n2] = __builtin_amdgcn_mfma_f32_16x16x32_bf16(bfv[n2], af[m], acc[m][n2], 0, 0, 0);
    }
    __syncthreads();
  }

  // ===== per-lane gated epilogue; LDS staging =====
  unsigned int* g1s = (unsigned int*)smem;            // [128][36] u32: (a,c) then (u1,u2)
  float*        g2s = (float*)(smem + 18432);         // [128][36] f32: bu

  const float ginv = __expf(lgam[0]) * inv_scale(sc, 0);
  float alpha[4], bd[4], bb[4], bc[4];
  #pragma unroll
  for (int nw = 0; nw < 4; nw++){
    int n = bn*32 + wc*16 + nw*4 + kgrp;
    alpha[nw] = softplusf(alog[n]);
    bd[nw] = dbias[n] + pnb[n];
    bb[nw] = pnb[N_ + n];
    bc[nw] = pnb[2*N_ + n];
  }
  #pragma unroll
  for (int mu = 0; mu < 4; mu++){
    const int tl = wr*64 + mu*16 + frow;
    #pragma unroll
    for (int nw = 0; nw < 4; nw++){
      const int nl = wc*16 + nw*4 + kgrp;
      f32x4 v = acc[mu][nw];
      float lp = __logf(1.f + __expf(v[1] + bd[nw]));
      float av = fminf(__expf(-alpha[nw]*lp), 1.f - 1e-4f);
      float bv = tanhrcpf(v[2] + bb[nw]);
      float cv = tanhrcpf(v[3] + bc[nw]);
      float p = av*av + cv*cv;
      float r = bv*bv;
      float q = av*bv;
      float pr = p - r;
      float disc = pr*pr + 4.f*q*q;
      float lam = 0.5f*(p + r + sqrtf(disc + 1e-12f));
      float inv = fminf(rsqrtf(lam + 1e-12f), 1.f);
      float a = av * inv;
      float c = cv * inv;
      float bu = (bv * inv) * (v[0] * ginv);
      g1s[tl*36 + nl] = (unsigned int)f2bf(a) | ((unsigned int)f2bf(c) << 16);
      g2s[tl*36 + nl] = bu;
    }
  }
  __syncthreads();
  // fused chunk scan: 256 threads = 8 chunks x 32 n; converts (a,c,bu) -> (u1,u2)
  // in place (g1s), accumulates chunk totals (Asum, Ssum).
  {
    const int chl = tid >> 5;          // 0..7
    const int nl  = tid & 31;          // 0..31
    float Ar = 1.f, Sr = 0.f;
    #pragma unroll
    for (int i = 0; i < 16; i++){
      int off = (chl*16 + i)*36 + nl;
      unsigned int pk = g1s[off];
      float a = bf2f((unsigned short)(pk & 0xffffu));
      float c = bf2f((unsigned short)(pk >> 16));
      float bu = g2s[off];
      g1s[off] = (unsigned int)f2bf(c*Ar) | ((unsigned int)f2bf(c*Sr) << 16);  // (u1,u2) at state BEFORE row i
      Sr = fmaf(a, Sr, bu);
      Ar *= a;
    }
    const size_t gch = (size_t)bm*8 + chl;        // global chunk = (b*NCH + ch)
    Asum[gch*N_ + bn*32 + nl] = Ar;
    Ssum[gch*N_ + bn*32 + nl] = Sr;
  }
  __syncthreads();
  // coalesced flush of packed U: 4 rounds x 256 threads = 128 rows x 8 segs x 16B
  const size_t t0b = (size_t)bm * 128;
  const int nb = bn*32;
  #pragma unroll
  for (int r = 0; r < 4; r++){
    int flat = r*256 + tid;
    int tl = flat >> 3, seg = flat & 7;
    uint4 v1 = *(const uint4*)(g1s + tl*36 + seg*4);
    *(uint4*)(U + (t0b + tl)*N_ + nb + seg*4) = v1;
  }
}

// ---- out-GEMM: C[M,N] = (A[M,K] * B[N,K]^T) * inv_scale(step)  (128^2, m97) ----
template<int OUTBF16>
__global__ __launch_bounds__(256) void k_gemm(
    const unsigned short* __restrict__ A,
    const unsigned short* __restrict__ Bmat,
    void* __restrict__ C0,
    int M, int N, int K,
    const float* __restrict__ sc, int step)
{
  __shared__ alignas(16) unsigned short As[128*64];
  __shared__ alignas(16) unsigned short Bs[128*64];
  const int tid = threadIdx.x;
  const int wid = tid >> 6;
  const int lane = tid & 63;
  const int bn = blockIdx.x, bm = blockIdx.y;

  char* C = (char*)C0;
  float outscale = (step >= 0) ? inv_scale(sc, step) : 1.f;

  const int wr = wid >> 1, wc = wid & 1;
  const int rg = lane >> 3;
  const int cby = (lane & 7) << 4;
  const int srow0 = wid * 32;
  const int frow = lane & 15;
  const int kgrp = lane >> 4;

  const unsigned short* ap[4];
  const unsigned short* bp[4];
  unsigned short* adst[4];
  unsigned short* bdst[4];
  #pragma unroll
  for (int i = 0; i < 4; i++){
    int r = srow0 + i*8 + rg;
    int cb = cby ^ ((r & 7) << 4);
    ap[i] = A    + (size_t)(bm*128 + r)*K + (cb >> 1);
    bp[i] = Bmat + (size_t)(bn*128 + r)*K + (cb >> 1);
    adst[i] = As + (srow0 + i*8)*64;
    bdst[i] = Bs + (srow0 + i*8)*64;
  }
  int aoff[4][2], boff[4][2];
  #pragma unroll
  for (int m = 0; m < 4; m++){
    int r = wr*64 + m*16 + frow;
    #pragma unroll
    for (int kk = 0; kk < 2; kk++)
      aoff[m][kk] = r*128 + ((kk*64 + kgrp*16) ^ ((r & 7) << 4));
  }
  #pragma unroll
  for (int n2 = 0; n2 < 4; n2++){
    int r = wc*64 + n2*16 + frow;
    #pragma unroll
    for (int kk = 0; kk < 2; kk++)
      boff[n2][kk] = r*128 + ((kk*64 + kgrp*16) ^ ((r & 7) << 4));
  }

  f32x4 acc[4][4] = {};

  for (int kt = 0; kt < K; kt += 64){
    #pragma unroll
    for (int i = 0; i < 4; i++){
      load_lds16(ap[i], adst[i]);
      load_lds16(bp[i], bdst[i]);
      ap[i] += 64; bp[i] += 64;
    }
    __syncthreads();
    #pragma unroll
    for (int kk = 0; kk < 2; kk++){
      bf16x8 af[4], bfv[4];
      #pragma unroll
      for (int m = 0; m < 4; m++)
        af[m] = *(const bf16x8*)((const char*)As + aoff[m][kk]);
      #pragma unroll
      for (int n2 = 0; n2 < 4; n2++)
        bfv[n2] = *(const bf16x8*)((const char*)Bs + boff[n2][kk]);
      #pragma unroll
      for (int m = 0; m < 4; m++)
        #pragma unroll
        for (int n2 = 0; n2 < 4; n2++)
          acc[m][n2] = __builtin_amdgcn_mfma_f32_16x16x32_bf16(af[m], bfv[n2], acc[m][n2], 0, 0, 0);
    }
    __syncthreads();
  }

  const int row0 = bm*128 + wr*64;
  const int col0 = bn*128 + wc*64 + frow;
  #pragma unroll
  for (int m = 0; m < 4; m++){
    #pragma unroll
    for (int n2 = 0; n2 < 4; n2++){
      const int col = col0 + n2*16;
      const int rb = row0 + m*16 + kgrp*4;
      #pragma unroll
      for (int j = 0; j < 4; j++){
        float v = acc[m][n2][j] * outscale;
        if (OUTBF16) ((unsigned short*)C)[(size_t)(rb + j)*N + col] = f2bf(v);
        else         ((float*)C)[(size_t)(rb + j)*N + col] = v;
      }
    }
  }
}

// ---- triangular squaring-chain GEMM (C = X*X^T symmetric, upper tiles only) ----
__global__ __launch_bounds__(256) void k_sq(
    const unsigned short* __restrict__ A0, unsigned short* __restrict__ C0,
    const unsigned short* __restrict__ A1, unsigned short* __restrict__ C1,
    float* __restrict__ sc, int step)
{
  __shared__ alignas(16) unsigned short As0[64*128], Bs0[64*128];
  __shared__ alignas(16) unsigned short As1[64*128], Bs1[64*128];
  const int tid = threadIdx.x;
  const int wid = tid >> 6;
  const int lane = tid & 63;
  const int z = blockIdx.z;

  int x = blockIdx.x, bm = 0;
  while (x >= 16 - bm){ x -= 16 - bm; bm++; }
  const int bn = bm + x;

  const unsigned short* A = z ? A1 : A0;
  unsigned short* C = z ? C1 : C0;
  const size_t rs = (step == 0 && z == 0) ? 4096 : 1024;
  float outscale = 1.f;
  if (step > 0){ float t = sc[8 + (step-1)*2 + z]; outscale = 1.f/(t*t); }

  const int wr = wid >> 1, wc = wid & 1;
  const int frow = lane & 15;
  const int kgrp = lane >> 4;

  const int srl = lane >> 4;
  const int sgr = lane & 15;
  const int swzr = wid*4 + srl;
  const int scol_e = ((sgr ^ swzr) << 3);

  const size_t Arow = (size_t)bm * 64;
  const size_t Brow = (size_t)bn * 64;

  f32x4 acc[2][2] = {};

  auto stage = [&](unsigned short* as, unsigned short* bs, int t){
    const int kt = t * 128;
    #pragma unroll
    for (int i = 0; i < 4; i++){
      int r = i*16 + wid*4 + srl;
      load_lds16(A + (Arow + r)*rs + kt + scol_e, as + (i*16 + wid*4)*128);
      load_lds16(A + (Brow + r)*rs + kt + scol_e, bs + (i*16 + wid*4)*128);
    }
  };

  auto compute = [&](const unsigned short* as, const unsigned short* bs){
    #pragma unroll
    for (int ks = 0; ks < 4; ks++){
      const int kb = ks*64 + kgrp*16;
      bf16x8 af[2], bfv[2];
      #pragma unroll
      for (int m = 0; m < 2; m++){
        int r = wr*32 + m*16 + frow;
        af[m] = *(const bf16x8*)((const char*)as + r*256 + (kb ^ (frow << 4)));
      }
      #pragma unroll
      for (int n2 = 0; n2 < 2; n2++){
        int r = wc*32 + n2*16 + frow;
        bfv[n2] = *(const bf16x8*)((const char*)bs + r*256 + (kb ^ (frow << 4)));
      }
      #pragma unroll
      for (int m = 0; m < 2; m++)
        #pragma unroll
        for (int n2 = 0; n2 < 2; n2++)
          acc[m][n2] = __builtin_amdgcn_mfma_f32_16x16x32_bf16(af[m], bfv[n2], acc[m][n2], 0, 0, 0);
    }
  };

  stage(As0, Bs0, 0);
  __syncthreads();
  for (int t2 = 0; t2 < 8; t2 += 2){
    if (t2 + 1 < 8) stage(As1, Bs1, t2 + 1);
    compute(As0, Bs0);
    __syncthreads();
    if (t2 + 2 < 8) stage(As0, Bs0, t2 + 2);
    compute(As1, Bs1);
    __syncthreads();
  }

  const int row0 = bm*64 + wr*32;
  const int col0 = bn*64 + wc*32 + frow;
  float fr = 0.f;
  #pragma unroll
  for (int m = 0; m < 2; m++){
    #pragma unroll
    for (int n2 = 0; n2 < 2; n2++){
      const int col = col0 + n2*16;
      const int rb = row0 + m*16 + kgrp*4;
      us4 tw;
      #pragma unroll
      for (int j = 0; j < 4; j++){
        float v = acc[m][n2][j] * outscale;
        unsigned short h = f2bf(v);
        C[(size_t)(rb + j)*1024 + col] = h;
        tw[j] = h;
        fr += v*v;
      }
      if (bm != bn)
        *(us4*)(C + (size_t)col*1024 + rb) = tw;
    }
  }
  if (bm == bn && wr == wc){
    int j = frow - kgrp*4;
    if (j >= 0 && j < 4){
      float d = (acc[0][0][j] + acc[1][1][j]) * outscale;
      atomicAdd(&sc[8 + step*2 + z], d);
    }
  }
  if (step == SQN){
    if (bm != bn) fr *= 2.f;
    #pragma unroll
    for (int off = 32; off; off >>= 1) fr += __shfl_down(fr, off, 64);
    if (lane == 0) atomicAdd(&sc[8 + 2*(SQN+1) + z], fr);
  }
}

// ---- k_emit: global prefix over Asum/Ssum + streaming yh = u1*z_c + u2 ----
// No gate math, no in-chunk recurrence (z_c fixed per chunk). grid (NCH, B_).
__global__ __launch_bounds__(256) void k_emit(
    const unsigned int* __restrict__ U,
    const float* __restrict__ Asum, const float* __restrict__ Ssum,
    const float* __restrict__ z0, unsigned short* __restrict__ yh)
{
  const int tid = threadIdx.x;
  const int n0 = tid*4;
  const int ch = blockIdx.x, b = blockIdx.y;
  float z[4];
  #pragma unroll
  for (int j = 0; j < 4; j++) z[j] = z0[b*N_ + n0 + j];
  for (int c2 = 0; c2 < ch; c2++){
    const size_t idx = (size_t)(b*NCH + c2)*N_ + n0;
    float4 Av = *(const float4*)(Asum + idx);
    float4 Sv = *(const float4*)(Ssum + idx);
    z[0] = fmaf(Av.x, z[0], Sv.x);
    z[1] = fmaf(Av.y, z[1], Sv.y);
    z[2] = fmaf(Av.z, z[2], Sv.z);
    z[3] = fmaf(Av.w, z[3], Sv.w);
  }
  const size_t base = (size_t)(b*T_ + ch*TC)*N_ + n0;
  const unsigned int* up = U + base;
  unsigned short* Y = yh + base;
  #pragma unroll 4
  for (int i = 0; i < TC; i++){
    uint4 pac = *(const uint4*)up;
    us4 ow;
    #pragma unroll
    for (int j = 0; j < 4; j++){
      unsigned int p = j==0 ? pac.x : j==1 ? pac.y : j==2 ? pac.z : pac.w;
      float u1 = bf2f((unsigned short)(p & 0xffffu));
      float u2 = bf2f((unsigned short)(p >> 16));
      ow[j] = f2bf(fmaf(u1, z[j], u2));
    }
    *(us4*)Y = ow;
    up += N_; Y += N_;
  }
}

extern "C" void kernel_launch(void* const* d_in, const int* in_sizes, int n_in,
                              void* d_out, int out_size, void* d_ws, size_t ws_size,
                              hipStream_t stream)
{
  const float* u    = (const float*)d_in[0];
  const float* z0   = (const float*)d_in[1];
  const float* Win  = (const float*)d_in[2];
  const float* Wout = (const float*)d_in[3];
  const float* pnw  = (const float*)d_in[4];
  const float* pnb  = (const float*)d_in[5];
  const float* alog = (const float*)d_in[6];
  const float* dbias= (const float*)d_in[7];
  const float* lgam = (const float*)d_in[8];

  char* ws = (char*)d_ws;
  size_t off = 0;
  auto alloc = [&](size_t bytes) -> void* {
    void* p = ws + off;
    off += (bytes + 255) & ~(size_t)255;
    return p;
  };
  float*          sc     = (float*)         alloc(1024);
  unsigned short* u16    = (unsigned short*)alloc((size_t)8192*1024*2);
  unsigned short* Wcat16 = (unsigned short*)alloc((size_t)4096*1024*2);
  unsigned short* Wout16 = (unsigned short*)alloc((size_t)1024*1024*2);
  unsigned int*   Upk    = (unsigned int*)  alloc((size_t)8192*1024*4);
  unsigned short* yh16   = (unsigned short*)alloc((size_t)8192*1024*2);
  unsigned short* Hping  = (unsigned short*)alloc((size_t)2*1024*1024*2);
  unsigned short* Hpong  = (unsigned short*)alloc((size_t)2*1024*1024*2);
  float*          Asum   = (float*)alloc((size_t)B_*NCH*N_*4);
  float*          Ssum   = (float*)alloc((size_t)B_*NCH*N_*4);

  k_convert_all<<<CONV_BLOCKS, 256, 0, stream>>>(u, Win, pnw, Wout, u16, Wcat16, Wout16, sc);

  // spectral-norm chains
  dim3 gsq(136, 1, 2);
  k_sq<<<gsq, 256, 0, stream>>>(Wcat16, Hping, Wout16, Hping + (size_t)1024*1024, sc, 0);
  unsigned short* hin = Hping;
  unsigned short* hout = Hpong;
  for (int s = 1; s <= SQN; s++){
    k_sq<<<gsq, 256, 0, stream>>>(hin, hout, hin + (size_t)1024*1024, hout + (size_t)1024*1024, sc, s);
    unsigned short* t = hin; hin = hout; hout = t;
  }

  // gated P-GEMM: epilogue emits packed (u1,u2) + chunk (Asum,Ssum)
  dim3 g1(4096/128, 8192/128);
  k_pgemm<<<g1, 256, 0, stream>>>(u16, Wcat16, alog, dbias, pnb, lgam, sc, Upk, Asum, Ssum);

  // prefix + streaming y_hat emit
  dim3 gb(NCH, B_);
  k_emit<<<gb, 256, 0, stream>>>(Upk, Asum, Ssum, z0, yh16);

  // y = (y_hat @ W_out^T) * inv_scale(sc,1)  (fp32 out)
  dim3 g2(1024/128, 8192/128);
  k_gemm<0><<<g2, 256, 0, stream>>>(yh16, Wout16, d_out, 8192, 1024, 1024, sc, 1);
}